// Round 1
// baseline (958.914 us; speedup 1.0000x reference)
//
#include <hip/hip_runtime.h>
#include <math.h>

#define BB_ 8
#define CC_ 256
#define HH_ 64
#define WW_ 64
#define HWSZ 4096            // 64*64
#define CHW (CC_*HWSZ)       // 1,048,576
#define BCHW (BB_*CHW)       // 8,388,608

struct Taps5 { float t[5]; };

// ---------------- utility ----------------
__global__ void zero_kernel(float* __restrict__ p, int n){
    int i = blockIdx.x*256 + threadIdx.x;
    if (i < n) p[i] = 0.f;
}

// ---------------- depthwise gaussian blur (zero-pad SAME) ----------------
template<int R>
__global__ __launch_bounds__(256) void blur_kernel(const float* __restrict__ in,
                                                   float* __restrict__ out, Taps5 taps){
    int idx = blockIdx.x*256 + threadIdx.x;
    if (idx >= BCHW) return;
    int w = idx & 63;
    int h = (idx >> 6) & 63;
    int bc = idx >> 12;
    const float* plane = in + (size_t)bc * HWSZ;
    float acc = 0.f;
    #pragma unroll
    for (int dy = -R; dy <= R; ++dy){
        int hy = h + dy;
        if (hy < 0 || hy >= HH_) continue;
        #pragma unroll
        for (int dx = -R; dx <= R; ++dx){
            int wx = w + dx;
            if (wx < 0 || wx >= WW_) continue;
            acc += taps.t[dy+R] * taps.t[dx+R] * plane[hy*64 + wx];
        }
    }
    out[idx] = acc;
}

// ---------------- row softmax over HW of L = P - (Q?) ----------------
// one block per (b*C + c) row; 256 threads, 16 elems each
template<bool HAS_Q>
__global__ __launch_bounds__(256) void rowsoftmax_kernel(const float* __restrict__ P,
                                                         const float* __restrict__ Q,
                                                         float* __restrict__ OUT){
    size_t base = (size_t)blockIdx.x * HWSZ;
    int tid = threadIdx.x;
    float v[16];
    float m = -INFINITY;
    #pragma unroll
    for (int r = 0; r < 16; ++r){
        float x = P[base + tid + r*256];
        if (HAS_Q) x -= Q[base + tid + r*256];
        v[r] = x;
        m = fmaxf(m, x);
    }
    #pragma unroll
    for (int off = 32; off > 0; off >>= 1) m = fmaxf(m, __shfl_xor(m, off));
    __shared__ float redm[4], reds[4];
    int wid = tid >> 6, lane = tid & 63;
    if (lane == 0) redm[wid] = m;
    __syncthreads();
    m = fmaxf(fmaxf(redm[0], redm[1]), fmaxf(redm[2], redm[3]));
    float s = 0.f;
    #pragma unroll
    for (int r = 0; r < 16; ++r){ v[r] = expf(v[r] - m); s += v[r]; }
    #pragma unroll
    for (int off = 32; off > 0; off >>= 1) s += __shfl_xor(s, off);
    if (lane == 0) reds[wid] = s;
    __syncthreads();
    s = reds[0] + reds[1] + reds[2] + reds[3];
    float inv = 1.f / s;
    #pragma unroll
    for (int r = 0; r < 16; ++r) OUT[base + tid + r*256] = v[r] * inv;
}

// ---------------- column softmax over C (in-place), for queries ----------------
// grid: B * (HW/64); block 256: cg = tid>>6 owns 64 channels, nl = tid&63 is spatial
__global__ __launch_bounds__(256) void colsoftmax_kernel(float* __restrict__ Q){
    int blk = blockIdx.x;
    int bb = blk >> 6;             // HW/64 = 64 chunks per batch
    int n0 = (blk & 63) * 64;
    int tid = threadIdx.x, cg = tid >> 6, nl = tid & 63;
    size_t base = (size_t)bb*CHW + n0 + nl;
    float m = -INFINITY, s = 0.f;
    for (int c = cg*64; c < cg*64 + 64; ++c){
        float x = Q[base + (size_t)c*HWSZ];
        float nm = fmaxf(m, x);
        s = s*expf(m - nm) + expf(x - nm);
        m = nm;
    }
    __shared__ float Ms[4][64], Ss[4][64];
    Ms[cg][nl] = m; Ss[cg][nl] = s;
    __syncthreads();
    float M = fmaxf(fmaxf(Ms[0][nl], Ms[1][nl]), fmaxf(Ms[2][nl], Ms[3][nl]));
    float S = 0.f;
    #pragma unroll
    for (int g = 0; g < 4; ++g) S += Ss[g][nl]*expf(Ms[g][nl] - M);
    float inv = 1.f / S;
    for (int c = cg*64; c < cg*64 + 64; ++c){
        size_t o = base + (size_t)c*HWSZ;
        Q[o] = expf(Q[o] - M) * inv;
    }
}

// ---------------- GEMM: Y[b,m,n] = sum_k Aeff[m,k]*X[b,k,n] (+bias) , M=K=256, N=4096
// AMODE 0: Aeff = A (shared [M,K] row-major)
// AMODE 1: Aeff[m,k] = A[b*65536 + k*256 + m]   (per-batch transposed 256x256)
// EPI 0: Y = acc + bias ; EPI 1: Y = wdw[2m]*(acc+bias[m]) ; EPI 2: Y += wdw[2m+1]*acc
template<int AMODE, int EPI>
__global__ __launch_bounds__(256) void gemm_kernel(const float* __restrict__ A,
                                                   const float* __restrict__ bias,
                                                   const float* __restrict__ X,
                                                   float* __restrict__ Y,
                                                   const float* __restrict__ wdw){
    const int bb = blockIdx.z;
    const int m0 = blockIdx.y * 64;
    const int n0 = blockIdx.x * 64;
    __shared__ float As[32][66];
    __shared__ float Xs[32][64];
    const int tid = threadIdx.x;
    const int tx = tid & 15, ty = tid >> 4;
    float acc[4][4] = {};
    for (int k0 = 0; k0 < 256; k0 += 32){
        if (AMODE == 0){
            int kk = tid & 31, ml = tid >> 5;
            #pragma unroll
            for (int r = 0; r < 8; ++r){
                int m = ml + r*8;
                As[kk][m] = A[(size_t)(m0+m)*256 + k0 + kk];
            }
        } else {
            int ml = tid & 63, kg = tid >> 6;
            #pragma unroll
            for (int r = 0; r < 8; ++r){
                int kk = kg + r*4;
                As[kk][ml] = A[(size_t)bb*65536 + (size_t)(k0+kk)*256 + m0 + ml];
            }
        }
        {
            int j = tid & 63, kg = tid >> 6;
            #pragma unroll
            for (int r = 0; r < 8; ++r){
                int kk = kg + r*4;
                Xs[kk][j] = X[(size_t)bb*CHW + (size_t)(k0+kk)*HWSZ + n0 + j];
            }
        }
        __syncthreads();
        #pragma unroll
        for (int kk = 0; kk < 32; ++kk){
            const float4 xv = *reinterpret_cast<const float4*>(&Xs[kk][tx*4]);
            const float2 a0 = *reinterpret_cast<const float2*>(&As[kk][ty*4]);
            const float2 a1 = *reinterpret_cast<const float2*>(&As[kk][ty*4+2]);
            float av[4] = {a0.x, a0.y, a1.x, a1.y};
            #pragma unroll
            for (int i = 0; i < 4; ++i){
                acc[i][0] += av[i]*xv.x;
                acc[i][1] += av[i]*xv.y;
                acc[i][2] += av[i]*xv.z;
                acc[i][3] += av[i]*xv.w;
            }
        }
        __syncthreads();
    }
    #pragma unroll
    for (int i = 0; i < 4; ++i){
        const int m = m0 + ty*4 + i;
        float add = 0.f;
        if (EPI != 2 && bias) add = bias[m];
        size_t o = (size_t)bb*CHW + (size_t)m*HWSZ + n0 + tx*4;
        float4* yp = reinterpret_cast<float4*>(&Y[o]);
        if (EPI == 0){
            float4 r2 = {acc[i][0]+add, acc[i][1]+add, acc[i][2]+add, acc[i][3]+add};
            *yp = r2;
        } else if (EPI == 1){
            float sc = wdw[2*m];
            float4 r2 = {sc*(acc[i][0]+add), sc*(acc[i][1]+add), sc*(acc[i][2]+add), sc*(acc[i][3]+add)};
            *yp = r2;
        } else {
            float sc = wdw[2*m + 1];
            float4 old = *yp;
            old.x += sc*acc[i][0]; old.y += sc*acc[i][1];
            old.z += sc*acc[i][2]; old.w += sc*acc[i][3];
            *yp = old;
        }
    }
}

// ---------------- gram: Gpart[z, m, d] = sum_{k in chunk} P[b,m,k]*(Sa-Sb)[b,d,k]
// M=N=256, K=4096 split into 8 chunks of 512 (z = b*8 + kc). Deterministic split-K.
template<bool HAS_SB>
__global__ __launch_bounds__(256) void gram_kernel(const float* __restrict__ P,
                                                   const float* __restrict__ Sa,
                                                   const float* __restrict__ Sb,
                                                   float* __restrict__ Gpart){
    const int z = blockIdx.z;
    const int bb = z >> 3;
    const int kc = z & 7;
    const int m0 = blockIdx.y * 64, d0 = blockIdx.x * 64;
    __shared__ float Ps[32][66];
    __shared__ float Qs[32][66];
    const int tid = threadIdx.x;
    const int tx = tid & 15, ty = tid >> 4;
    float acc[4][4] = {};
    const int kbeg = kc * 512, kend = kbeg + 512;
    for (int k0 = kbeg; k0 < kend; k0 += 32){
        int kk = tid & 31, ml = tid >> 5;
        #pragma unroll
        for (int r = 0; r < 8; ++r){
            int m = ml + r*8;
            Ps[kk][m] = P[(size_t)bb*CHW + (size_t)(m0+m)*HWSZ + k0 + kk];
            float q = Sa[(size_t)bb*CHW + (size_t)(d0+m)*HWSZ + k0 + kk];
            if (HAS_SB) q -= Sb[(size_t)bb*CHW + (size_t)(d0+m)*HWSZ + k0 + kk];
            Qs[kk][m] = q;
        }
        __syncthreads();
        #pragma unroll
        for (int kk2 = 0; kk2 < 32; ++kk2){
            float2 a0 = *reinterpret_cast<const float2*>(&Ps[kk2][ty*4]);
            float2 a1 = *reinterpret_cast<const float2*>(&Ps[kk2][ty*4+2]);
            float2 b0 = *reinterpret_cast<const float2*>(&Qs[kk2][tx*4]);
            float2 b1 = *reinterpret_cast<const float2*>(&Qs[kk2][tx*4+2]);
            float av[4] = {a0.x, a0.y, a1.x, a1.y};
            float bw[4] = {b0.x, b0.y, b1.x, b1.y};
            #pragma unroll
            for (int i = 0; i < 4; ++i)
                #pragma unroll
                for (int j = 0; j < 4; ++j)
                    acc[i][j] += av[i]*bw[j];
        }
        __syncthreads();
    }
    #pragma unroll
    for (int i = 0; i < 4; ++i){
        float4 r2 = {acc[i][0], acc[i][1], acc[i][2], acc[i][3]};
        *reinterpret_cast<float4*>(&Gpart[(size_t)z*65536 + (size_t)(m0+ty*4+i)*256 + d0 + tx*4]) = r2;
    }
}

// reduce 8 split-K partials: G[b,i] = sum_kc Gpart[b*8+kc, i]
__global__ void reduce8_kernel(const float* __restrict__ part, float* __restrict__ G){
    int i = blockIdx.x*256 + threadIdx.x;   // over B*65536 = 524288
    if (i >= BB_*65536) return;
    int b = i >> 16; int r = i & 65535;
    float s = 0.f;
    #pragma unroll
    for (int kc = 0; kc < 8; ++kc) s += part[((size_t)(b*8 + kc))*65536 + r];
    G[i] = s;
}

// ---------------- att[b,c,:] += softmax(Atmp[b,c,:]) over last dim (256) ----------------
__global__ __launch_bounds__(256) void att_acc_kernel(const float* __restrict__ Atmp,
                                                      float* __restrict__ att){
    int row = blockIdx.x;   // b*C + c
    int tid = threadIdx.x;
    float v = Atmp[(size_t)row*256 + tid];
    float m = v;
    #pragma unroll
    for (int off = 32; off > 0; off >>= 1) m = fmaxf(m, __shfl_xor(m, off));
    __shared__ float redm[4], reds[4];
    int wid = tid >> 6, lane = tid & 63;
    if (lane == 0) redm[wid] = m;
    __syncthreads();
    m = fmaxf(fmaxf(redm[0], redm[1]), fmaxf(redm[2], redm[3]));
    float e = expf(v - m);
    float s = e;
    #pragma unroll
    for (int off = 32; off > 0; off >>= 1) s += __shfl_xor(s, off);
    if (lane == 0) reds[wid] = s;
    __syncthreads();
    s = reds[0] + reds[1] + reds[2] + reds[3];
    att[(size_t)row*256 + tid] += e / s;
}

// ---------------- host ----------------
extern "C" void kernel_launch(void* const* d_in, const int* in_sizes, int n_in,
                              void* d_out, int out_size, void* d_ws, size_t ws_size,
                              hipStream_t stream){
    const float* x   = (const float*)d_in[0];
    const float* Wk  = (const float*)d_in[1];
    const float* bk  = (const float*)d_in[2];
    const float* Wq  = (const float*)d_in[3];
    const float* bq  = (const float*)d_in[4];
    const float* Wv  = (const float*)d_in[5];
    const float* bv  = (const float*)d_in[6];
    const float* Wr  = (const float*)d_in[7];
    const float* br  = (const float*)d_in[8];
    const float* wdw = (const float*)d_in[9];
    float* out = (float*)d_out;

    float* ws   = (float*)d_ws;
    float* bufA = ws;                               // 8,388,608 f  (G1 / keys / attended)
    float* bufB = bufA + (size_t)BCHW;              // 8,388,608 f  (G2 / values)
    float* bufC = bufB + (size_t)BCHW;              // 8,388,608 f  (SM rows / queries)
    float* attb = bufC + (size_t)BCHW;              // 524,288 f
    float* ctxb = attb + (size_t)(BB_*65536);       // 524,288 f (Atmp / context)
    float* part = out;                              // split-K partials: 4,194,304 f <= out (8.39M f)

    // gaussian taps (host-computed, float64 like numpy then cast)
    Taps5 T3{}, T5{};
    {
        double g[5], s;
        s = 0; for (int i = 0; i < 3; ++i){ double d = i - 1.0; g[i] = exp(-d*d/(2.0*1.6*1.6)); s += g[i]; }
        for (int i = 0; i < 3; ++i) T3.t[i] = (float)(g[i]/s);
        double sig = 1.6 * pow(2.0, 1.0/3.0);
        s = 0; for (int i = 0; i < 5; ++i){ double d = i - 2.0; g[i] = exp(-d*d/(2.0*sig*sig)); s += g[i]; }
        for (int i = 0; i < 5; ++i) T5.t[i] = (float)(g[i]/s);
    }

    const dim3 blk(256);
    const dim3 gGemm(64, 4, BB_);
    const dim3 gGram(4, 4, BB_*8);

    // pyramid
    blur_kernel<1><<<BCHW/256, blk, 0, stream>>>(x, bufA, T3);      // G1
    blur_kernel<2><<<BCHW/256, blk, 0, stream>>>(bufA, bufB, T5);   // G2

    zero_kernel<<<(BB_*65536)/256, blk, 0, stream>>>(attb, BB_*65536);

    // chan_att(x)
    rowsoftmax_kernel<false><<<BB_*CC_, blk, 0, stream>>>(x, nullptr, bufC);
    gram_kernel<false><<<gGram, blk, 0, stream>>>(bufC, x, nullptr, part);
    reduce8_kernel<<<(BB_*65536)/256, blk, 0, stream>>>(part, ctxb);
    att_acc_kernel<<<BB_*CC_, blk, 0, stream>>>(ctxb, attb);
    // chan_att(x - G1)
    rowsoftmax_kernel<true><<<BB_*CC_, blk, 0, stream>>>(x, bufA, bufC);
    gram_kernel<true><<<gGram, blk, 0, stream>>>(bufC, x, bufA, part);
    reduce8_kernel<<<(BB_*65536)/256, blk, 0, stream>>>(part, ctxb);
    att_acc_kernel<<<BB_*CC_, blk, 0, stream>>>(ctxb, attb);
    // chan_att(G1 - G2)
    rowsoftmax_kernel<true><<<BB_*CC_, blk, 0, stream>>>(bufA, bufB, bufC);
    gram_kernel<true><<<gGram, blk, 0, stream>>>(bufC, bufA, bufB, part);
    reduce8_kernel<<<(BB_*65536)/256, blk, 0, stream>>>(part, ctxb);
    att_acc_kernel<<<BB_*CC_, blk, 0, stream>>>(ctxb, attb);

    // keys = rowsoftmax(Wk@x + bk)   (bufA now free)
    gemm_kernel<0,0><<<gGemm, blk, 0, stream>>>(Wk, bk, x, bufA, nullptr);
    rowsoftmax_kernel<false><<<BB_*CC_, blk, 0, stream>>>(bufA, nullptr, bufA);
    // values = Wv@x + bv
    gemm_kernel<0,0><<<gGemm, blk, 0, stream>>>(Wv, bv, x, bufB, nullptr);
    // context = keys @ values^T
    gram_kernel<false><<<gGram, blk, 0, stream>>>(bufA, bufB, nullptr, part);
    reduce8_kernel<<<(BB_*65536)/256, blk, 0, stream>>>(part, ctxb);
    // queries = colsoftmax(Wq@x + bq)
    gemm_kernel<0,0><<<gGemm, blk, 0, stream>>>(Wq, bq, x, bufC, nullptr);
    colsoftmax_kernel<<<BB_*64, blk, 0, stream>>>(bufC);
    // attended = ctx^T @ queries  -> bufA
    gemm_kernel<1,0><<<gGemm, blk, 0, stream>>>(ctxb, nullptr, bufC, bufA, nullptr);
    // out = wdw0 * (Wr@attended + br)
    gemm_kernel<0,1><<<gGemm, blk, 0, stream>>>(Wr, br, bufA, out, wdw);
    // out += wdw1 * (att^T @ queries)
    gemm_kernel<1,2><<<gGemm, blk, 0, stream>>>(attb, nullptr, bufC, out, wdw);
}

// Round 2
// 593.382 us; speedup vs baseline: 1.6160x; 1.6160x over previous
//
#include <hip/hip_runtime.h>
#include <math.h>

#define BB_ 8
#define CC_ 256
#define HWSZ 4096            // 64*64
#define CHW (CC_*HWSZ)       // 1,048,576
#define BCHW (BB_*CHW)       // 8,388,608

struct Taps5 { float t[5]; };

// ---------------- utility ----------------
__global__ void zero_kernel(float* __restrict__ p, int n){
    int i = blockIdx.x*256 + threadIdx.x;
    if (i < n) p[i] = 0.f;
}

// ---------------- fused pyramid + softmax(x), per (b,c) plane ----------------
// writes P0 = softmax(x over plane), L1 = x - G1, L2 = G1 - G2
__global__ __launch_bounds__(256) void plane_kernel(const float* __restrict__ x,
        float* __restrict__ P0, float* __restrict__ L1o, float* __restrict__ L2o,
        Taps5 t3, Taps5 t5){
    const size_t base = (size_t)blockIdx.x * HWSZ;
    const int tid = threadIdx.x;
    const int r  = tid >> 2;           // 0..63
    const int cq = (tid & 3) * 16;     // 0,16,32,48
    __shared__ float X[64*65];
    __shared__ float T[64*65];
    __shared__ float G[64*65];
    #pragma unroll
    for (int i = 0; i < 4; ++i){
        float4 v = *reinterpret_cast<const float4*>(&x[base + r*64 + cq + i*4]);
        X[r*65 + cq + i*4 + 0] = v.x;
        X[r*65 + cq + i*4 + 1] = v.y;
        X[r*65 + cq + i*4 + 2] = v.z;
        X[r*65 + cq + i*4 + 3] = v.w;
    }
    __syncthreads();
    // horizontal 3-tap (zero pad)
    #pragma unroll
    for (int j = 0; j < 16; ++j){
        int c = cq + j;
        float l = (c > 0)  ? X[r*65 + c - 1] : 0.f;
        float m = X[r*65 + c];
        float rr = (c < 63) ? X[r*65 + c + 1] : 0.f;
        T[r*65 + c] = t3.t[0]*l + t3.t[1]*m + t3.t[2]*rr;
    }
    __syncthreads();
    // vertical 3-tap -> G (= G1)
    #pragma unroll
    for (int j = 0; j < 16; ++j){
        int c = cq + j;
        float u = (r > 0)  ? T[(r-1)*65 + c] : 0.f;
        float m = T[r*65 + c];
        float d = (r < 63) ? T[(r+1)*65 + c] : 0.f;
        G[r*65 + c] = t3.t[0]*u + t3.t[1]*m + t3.t[2]*d;
    }
    __syncthreads();
    // horizontal 5-tap on G -> T
    #pragma unroll
    for (int j = 0; j < 16; ++j){
        int c = cq + j;
        float acc = 0.f;
        #pragma unroll
        for (int d = -2; d <= 2; ++d){
            int cc = c + d;
            float v = (cc >= 0 && cc < 64) ? G[r*65 + cc] : 0.f;
            acc += t5.t[d+2]*v;
        }
        T[r*65 + c] = acc;
    }
    __syncthreads();
    // vertical 5-tap -> g2 (regs); compute v0/v1/v2
    float v0[16], v1[16], v2[16];
    float mx = -INFINITY;
    #pragma unroll
    for (int j = 0; j < 16; ++j){
        int c = cq + j;
        float g2 = 0.f;
        #pragma unroll
        for (int d = -2; d <= 2; ++d){
            int rr2 = r + d;
            float v = (rr2 >= 0 && rr2 < 64) ? T[rr2*65 + c] : 0.f;
            g2 += t5.t[d+2]*v;
        }
        float xv = X[r*65 + c];
        float g1 = G[r*65 + c];
        v0[j] = xv;
        v1[j] = xv - g1;
        v2[j] = g1 - g2;
        mx = fmaxf(mx, xv);
    }
    // block softmax of v0
    #pragma unroll
    for (int off = 32; off > 0; off >>= 1) mx = fmaxf(mx, __shfl_xor(mx, off));
    __shared__ float redm[4], reds[4];
    int wid = tid >> 6, lane = tid & 63;
    if (lane == 0) redm[wid] = mx;
    __syncthreads();
    mx = fmaxf(fmaxf(redm[0], redm[1]), fmaxf(redm[2], redm[3]));
    float s = 0.f;
    #pragma unroll
    for (int j = 0; j < 16; ++j){ v0[j] = expf(v0[j] - mx); s += v0[j]; }
    #pragma unroll
    for (int off = 32; off > 0; off >>= 1) s += __shfl_xor(s, off);
    if (lane == 0) reds[wid] = s;
    __syncthreads();
    s = reds[0] + reds[1] + reds[2] + reds[3];
    float inv = 1.f / s;
    size_t o = base + r*64 + cq;
    #pragma unroll
    for (int i = 0; i < 4; ++i){
        float4 p = {v0[i*4+0]*inv, v0[i*4+1]*inv, v0[i*4+2]*inv, v0[i*4+3]*inv};
        float4 a = {v1[i*4+0], v1[i*4+1], v1[i*4+2], v1[i*4+3]};
        float4 b = {v2[i*4+0], v2[i*4+1], v2[i*4+2], v2[i*4+3]};
        *reinterpret_cast<float4*>(&P0[o + i*4])  = p;
        *reinterpret_cast<float4*>(&L1o[o + i*4]) = a;
        *reinterpret_cast<float4*>(&L2o[o + i*4]) = b;
    }
}

// ---------------- row softmax over HW ----------------
template<bool HAS_Q>
__global__ __launch_bounds__(256) void rowsoftmax_kernel(const float* __restrict__ P,
                                                         const float* __restrict__ Q,
                                                         float* __restrict__ OUT){
    size_t base = (size_t)blockIdx.x * HWSZ;
    int tid = threadIdx.x;
    float v[16];
    float m = -INFINITY;
    #pragma unroll
    for (int r = 0; r < 16; ++r){
        float x = P[base + tid + r*256];
        if (HAS_Q) x -= Q[base + tid + r*256];
        v[r] = x;
        m = fmaxf(m, x);
    }
    #pragma unroll
    for (int off = 32; off > 0; off >>= 1) m = fmaxf(m, __shfl_xor(m, off));
    __shared__ float redm[4], reds[4];
    int wid = tid >> 6, lane = tid & 63;
    if (lane == 0) redm[wid] = m;
    __syncthreads();
    m = fmaxf(fmaxf(redm[0], redm[1]), fmaxf(redm[2], redm[3]));
    float s = 0.f;
    #pragma unroll
    for (int r = 0; r < 16; ++r){ v[r] = expf(v[r] - m); s += v[r]; }
    #pragma unroll
    for (int off = 32; off > 0; off >>= 1) s += __shfl_xor(s, off);
    if (lane == 0) reds[wid] = s;
    __syncthreads();
    s = reds[0] + reds[1] + reds[2] + reds[3];
    float inv = 1.f / s;
    #pragma unroll
    for (int r = 0; r < 16; ++r) OUT[base + tid + r*256] = v[r] * inv;
}

// ---------------- column softmax over C (in-place) ----------------
__global__ __launch_bounds__(256) void colsoftmax_kernel(float* __restrict__ Q){
    int blk = blockIdx.x;
    int bb = blk >> 6;
    int n0 = (blk & 63) * 64;
    int tid = threadIdx.x, cg = tid >> 6, nl = tid & 63;
    size_t base = (size_t)bb*CHW + n0 + nl;
    float m = -INFINITY, s = 0.f;
    for (int c = cg*64; c < cg*64 + 64; ++c){
        float x = Q[base + (size_t)c*HWSZ];
        float nm = fmaxf(m, x);
        s = s*expf(m - nm) + expf(x - nm);
        m = nm;
    }
    __shared__ float Ms[4][64], Ss[4][64];
    Ms[cg][nl] = m; Ss[cg][nl] = s;
    __syncthreads();
    float M = fmaxf(fmaxf(Ms[0][nl], Ms[1][nl]), fmaxf(Ms[2][nl], Ms[3][nl]));
    float S = 0.f;
    #pragma unroll
    for (int g = 0; g < 4; ++g) S += Ss[g][nl]*expf(Ms[g][nl] - M);
    float inv = 1.f / S;
    for (int c = cg*64; c < cg*64 + 64; ++c){
        size_t o = base + (size_t)c*HWSZ;
        Q[o] = expf(Q[o] - M) * inv;
    }
}

// ---------------- GEMM 128x128 tile: Y[b,m,n] = sum_k Aeff[m,k]*X[b,k,n] + epi ----------------
// AMODE 0: A shared [256][256] row-major; AMODE 1: A per-batch (stride 65536) row-major
// EPI 0: + bias[m] ; EPI 1: + wdw[2m]*bias[m]
template<int AMODE, int EPI>
__global__ __launch_bounds__(256) void gemm128_kernel(const float* __restrict__ A,
        const float* __restrict__ bias, const float* __restrict__ X,
        float* __restrict__ Y, const float* __restrict__ wdw){
    const int bb = blockIdx.z;
    const int m0 = blockIdx.y * 128;
    const int n0 = blockIdx.x * 128;
    const float* Ab = (AMODE == 1) ? A + (size_t)bb*65536 : A;
    const float* Xb = X + (size_t)bb*CHW;
    __shared__ float As[16*132];
    __shared__ float Xs[16*132];
    const int tid = threadIdx.x;
    const int tx = tid & 15, ty = tid >> 4;
    const int rowA = tid >> 1, koffA = (tid & 1) * 8;
    const int kkX = tid >> 4, noffX = (tid & 15) * 8;
    float acc[8][8] = {};
    for (int k0 = 0; k0 < 256; k0 += 16){
        float4 a0 = *(const float4*)&Ab[(size_t)(m0+rowA)*256 + k0 + koffA];
        float4 a1 = *(const float4*)&Ab[(size_t)(m0+rowA)*256 + k0 + koffA + 4];
        float4 x0 = *(const float4*)&Xb[(size_t)(k0+kkX)*4096 + n0 + noffX];
        float4 x1 = *(const float4*)&Xb[(size_t)(k0+kkX)*4096 + n0 + noffX + 4];
        As[(koffA+0)*132 + rowA] = a0.x;
        As[(koffA+1)*132 + rowA] = a0.y;
        As[(koffA+2)*132 + rowA] = a0.z;
        As[(koffA+3)*132 + rowA] = a0.w;
        As[(koffA+4)*132 + rowA] = a1.x;
        As[(koffA+5)*132 + rowA] = a1.y;
        As[(koffA+6)*132 + rowA] = a1.z;
        As[(koffA+7)*132 + rowA] = a1.w;
        *(float4*)&Xs[kkX*132 + noffX]     = x0;
        *(float4*)&Xs[kkX*132 + noffX + 4] = x1;
        __syncthreads();
        #pragma unroll
        for (int kk = 0; kk < 16; ++kk){
            float4 pa0 = *(const float4*)&As[kk*132 + ty*4];
            float4 pa1 = *(const float4*)&As[kk*132 + 64 + ty*4];
            float4 pb0 = *(const float4*)&Xs[kk*132 + tx*4];
            float4 pb1 = *(const float4*)&Xs[kk*132 + 64 + tx*4];
            float av[8] = {pa0.x,pa0.y,pa0.z,pa0.w,pa1.x,pa1.y,pa1.z,pa1.w};
            float bw[8] = {pb0.x,pb0.y,pb0.z,pb0.w,pb1.x,pb1.y,pb1.z,pb1.w};
            #pragma unroll
            for (int i = 0; i < 8; ++i)
                #pragma unroll
                for (int j = 0; j < 8; ++j)
                    acc[i][j] += av[i]*bw[j];
        }
        __syncthreads();
    }
    #pragma unroll
    for (int i = 0; i < 8; ++i){
        int m = m0 + ((i < 4) ? (ty*4 + i) : (64 + ty*4 + i - 4));
        float add = (EPI == 0) ? bias[m] : wdw[2*m]*bias[m];
        size_t o = (size_t)bb*CHW + (size_t)m*4096 + n0;
        float4 w0 = {acc[i][0]+add, acc[i][1]+add, acc[i][2]+add, acc[i][3]+add};
        float4 w1 = {acc[i][4]+add, acc[i][5]+add, acc[i][6]+add, acc[i][7]+add};
        *(float4*)&Y[o + tx*4]      = w0;
        *(float4*)&Y[o + 64 + tx*4] = w1;
    }
}

// ---------------- gram 128x128: part[z,m,d] = sum_{k in chunk} P[b,m,k]*S[b,d,k] ----------------
// z = b*16 + kc, chunk = 256
__global__ __launch_bounds__(256) void gram128_kernel(const float* __restrict__ P,
        const float* __restrict__ S, float* __restrict__ part){
    const int z = blockIdx.z;
    const int bb = z >> 4, kc = z & 15;
    const int m0 = blockIdx.y * 128, d0 = blockIdx.x * 128;
    const float* Pb = P + (size_t)bb*CHW;
    const float* Sb = S + (size_t)bb*CHW;
    __shared__ float Ps[16*132];
    __shared__ float Ss[16*132];
    const int tid = threadIdx.x;
    const int tx = tid & 15, ty = tid >> 4;
    const int row = tid >> 1, koff = (tid & 1) * 8;
    float acc[8][8] = {};
    const int kbeg = kc * 256;
    for (int k0 = kbeg; k0 < kbeg + 256; k0 += 16){
        float4 p0 = *(const float4*)&Pb[(size_t)(m0+row)*4096 + k0 + koff];
        float4 p1 = *(const float4*)&Pb[(size_t)(m0+row)*4096 + k0 + koff + 4];
        float4 s0 = *(const float4*)&Sb[(size_t)(d0+row)*4096 + k0 + koff];
        float4 s1 = *(const float4*)&Sb[(size_t)(d0+row)*4096 + k0 + koff + 4];
        Ps[(koff+0)*132 + row] = p0.x;
        Ps[(koff+1)*132 + row] = p0.y;
        Ps[(koff+2)*132 + row] = p0.z;
        Ps[(koff+3)*132 + row] = p0.w;
        Ps[(koff+4)*132 + row] = p1.x;
        Ps[(koff+5)*132 + row] = p1.y;
        Ps[(koff+6)*132 + row] = p1.z;
        Ps[(koff+7)*132 + row] = p1.w;
        Ss[(koff+0)*132 + row] = s0.x;
        Ss[(koff+1)*132 + row] = s0.y;
        Ss[(koff+2)*132 + row] = s0.z;
        Ss[(koff+3)*132 + row] = s0.w;
        Ss[(koff+4)*132 + row] = s1.x;
        Ss[(koff+5)*132 + row] = s1.y;
        Ss[(koff+6)*132 + row] = s1.z;
        Ss[(koff+7)*132 + row] = s1.w;
        __syncthreads();
        #pragma unroll
        for (int kk = 0; kk < 16; ++kk){
            float4 pa0 = *(const float4*)&Ps[kk*132 + ty*4];
            float4 pa1 = *(const float4*)&Ps[kk*132 + 64 + ty*4];
            float4 pb0 = *(const float4*)&Ss[kk*132 + tx*4];
            float4 pb1 = *(const float4*)&Ss[kk*132 + 64 + tx*4];
            float av[8] = {pa0.x,pa0.y,pa0.z,pa0.w,pa1.x,pa1.y,pa1.z,pa1.w};
            float bw[8] = {pb0.x,pb0.y,pb0.z,pb0.w,pb1.x,pb1.y,pb1.z,pb1.w};
            #pragma unroll
            for (int i = 0; i < 8; ++i)
                #pragma unroll
                for (int j = 0; j < 8; ++j)
                    acc[i][j] += av[i]*bw[j];
        }
        __syncthreads();
    }
    #pragma unroll
    for (int i = 0; i < 8; ++i){
        int m = m0 + ((i < 4) ? (ty*4 + i) : (64 + ty*4 + i - 4));
        size_t o = (size_t)z*65536 + (size_t)m*256 + d0;
        float4 w0 = {acc[i][0], acc[i][1], acc[i][2], acc[i][3]};
        float4 w1 = {acc[i][4], acc[i][5], acc[i][6], acc[i][7]};
        *(float4*)&part[o + tx*4]      = w0;
        *(float4*)&part[o + 64 + tx*4] = w1;
    }
}

// reduce 16 split-K partials
__global__ void reduce16_kernel(const float* __restrict__ part, float* __restrict__ G){
    int i = blockIdx.x*256 + threadIdx.x;    // over B*65536
    if (i >= BB_*65536) return;
    int b = i >> 16; int r = i & 65535;
    float s = 0.f;
    #pragma unroll
    for (int kc = 0; kc < 16; ++kc) s += part[((size_t)(b*16 + kc))*65536 + r];
    G[i] = s;
}

// att[b,c,:] += softmax(Atmp[b,c,:]) over last dim (256)
__global__ __launch_bounds__(256) void att_acc_kernel(const float* __restrict__ Atmp,
                                                      float* __restrict__ att){
    int row = blockIdx.x;
    int tid = threadIdx.x;
    float v = Atmp[(size_t)row*256 + tid];
    float m = v;
    #pragma unroll
    for (int off = 32; off > 0; off >>= 1) m = fmaxf(m, __shfl_xor(m, off));
    __shared__ float redm[4], reds[4];
    int wid = tid >> 6, lane = tid & 63;
    if (lane == 0) redm[wid] = m;
    __syncthreads();
    m = fmaxf(fmaxf(redm[0], redm[1]), fmaxf(redm[2], redm[3]));
    float e = expf(v - m);
    float s = e;
    #pragma unroll
    for (int off = 32; off > 0; off >>= 1) s += __shfl_xor(s, off);
    if (lane == 0) reds[wid] = s;
    __syncthreads();
    s = reds[0] + reds[1] + reds[2] + reds[3];
    att[(size_t)row*256 + tid] += e / s;
}

// ---------------- small NT gemm 256x256x256 per-batch ----------------
// C[b,m,n] = sum_l Aeff[m,l]*Beff[n,l] + epi
// EPI 0: + bias[n] ; EPI 1: wdw[2m]*acc + wdw[2m+1]*att[b,n,m]
template<int ABATCH, int BBATCH, int EPI>
__global__ __launch_bounds__(256) void nt256_kernel(const float* __restrict__ A,
        const float* __restrict__ B, const float* __restrict__ bias,
        const float* __restrict__ att, const float* __restrict__ wdw,
        float* __restrict__ C){
    const int bb = blockIdx.z;
    const int m0 = blockIdx.y * 64, n0 = blockIdx.x * 64;
    const float* Ab = ABATCH ? A + (size_t)bb*65536 : A;
    const float* Bb = BBATCH ? B + (size_t)bb*65536 : B;
    __shared__ float Au[32*68];
    __shared__ float Bu[32*68];
    const int tid = threadIdx.x;
    const int tx = tid & 15, ty = tid >> 4;
    const int row = tid >> 2, loff = (tid & 3) * 8;
    float acc[4][4] = {};
    for (int k0 = 0; k0 < 256; k0 += 32){
        float4 a0 = *(const float4*)&Ab[(size_t)(m0+row)*256 + k0 + loff];
        float4 a1 = *(const float4*)&Ab[(size_t)(m0+row)*256 + k0 + loff + 4];
        float4 b0 = *(const float4*)&Bb[(size_t)(n0+row)*256 + k0 + loff];
        float4 b1 = *(const float4*)&Bb[(size_t)(n0+row)*256 + k0 + loff + 4];
        Au[(loff+0)*68 + row] = a0.x;
        Au[(loff+1)*68 + row] = a0.y;
        Au[(loff+2)*68 + row] = a0.z;
        Au[(loff+3)*68 + row] = a0.w;
        Au[(loff+4)*68 + row] = a1.x;
        Au[(loff+5)*68 + row] = a1.y;
        Au[(loff+6)*68 + row] = a1.z;
        Au[(loff+7)*68 + row] = a1.w;
        Bu[(loff+0)*68 + row] = b0.x;
        Bu[(loff+1)*68 + row] = b0.y;
        Bu[(loff+2)*68 + row] = b0.z;
        Bu[(loff+3)*68 + row] = b0.w;
        Bu[(loff+4)*68 + row] = b1.x;
        Bu[(loff+5)*68 + row] = b1.y;
        Bu[(loff+6)*68 + row] = b1.z;
        Bu[(loff+7)*68 + row] = b1.w;
        __syncthreads();
        #pragma unroll
        for (int kk = 0; kk < 32; ++kk){
            float4 av = *(const float4*)&Au[kk*68 + ty*4];
            float4 bv = *(const float4*)&Bu[kk*68 + tx*4];
            float aa[4] = {av.x, av.y, av.z, av.w};
            float bb2[4] = {bv.x, bv.y, bv.z, bv.w};
            #pragma unroll
            for (int i = 0; i < 4; ++i)
                #pragma unroll
                for (int j = 0; j < 4; ++j)
                    acc[i][j] += aa[i]*bb2[j];
        }
        __syncthreads();
    }
    #pragma unroll
    for (int i = 0; i < 4; ++i){
        int m = m0 + ty*4 + i;
        float4 w;
        float* wp = &w.x;
        #pragma unroll
        for (int j = 0; j < 4; ++j){
            int n = n0 + tx*4 + j;
            float v = acc[i][j];
            if (EPI == 0) v += bias[n];
            else v = wdw[2*m]*v + wdw[2*m+1]*att[(size_t)bb*65536 + (size_t)n*256 + m];
            wp[j] = v;
        }
        *(float4*)&C[(size_t)bb*65536 + (size_t)m*256 + n0 + tx*4] = w;
    }
}

// ---------------- host ----------------
extern "C" void kernel_launch(void* const* d_in, const int* in_sizes, int n_in,
                              void* d_out, int out_size, void* d_ws, size_t ws_size,
                              hipStream_t stream){
    const float* x   = (const float*)d_in[0];
    const float* Wk  = (const float*)d_in[1];
    const float* bk  = (const float*)d_in[2];
    const float* Wq  = (const float*)d_in[3];
    const float* bq  = (const float*)d_in[4];
    const float* Wv  = (const float*)d_in[5];
    const float* bv  = (const float*)d_in[6];
    const float* Wr  = (const float*)d_in[7];
    const float* br  = (const float*)d_in[8];
    const float* wdw = (const float*)d_in[9];
    float* out = (float*)d_out;

    float* ws = (float*)d_ws;
    float* W0 = ws;                         // P0 / softmax(L) scratch
    float* W1 = W0 + (size_t)BCHW;          // L1 / keys
    float* W2 = W1 + (size_t)BCHW;          // L2 / queries
    float* S0 = W2 + (size_t)BCHW;          // attb  (B*256*256)
    float* S1 = S0 + (size_t)(BB_*65536);   // Atmp / KX / Mb
    float* S2 = S1 + (size_t)(BB_*65536);   // ctx
    float* part = out;                      // 128*65536 = out_size exactly

    Taps5 T3{}, T5{};
    {
        double g[5], s;
        s = 0; for (int i = 0; i < 3; ++i){ double d = i - 1.0; g[i] = exp(-d*d/(2.0*1.6*1.6)); s += g[i]; }
        for (int i = 0; i < 3; ++i) T3.t[i] = (float)(g[i]/s);
        double sig = 1.6 * pow(2.0, 1.0/3.0);
        s = 0; for (int i = 0; i < 5; ++i){ double d = i - 2.0; g[i] = exp(-d*d/(2.0*sig*sig)); s += g[i]; }
        for (int i = 0; i < 5; ++i) T5.t[i] = (float)(g[i]/s);
    }

    const dim3 blk(256);
    const dim3 gGemm(32, 2, BB_);
    const dim3 gGram(2, 2, BB_*16);
    const dim3 gNT(4, 4, BB_);

    // fused pyramid: P0 = softmax(x), L1 = x-G1, L2 = G1-G2
    plane_kernel<<<BB_*CC_, blk, 0, stream>>>(x, W0, W1, W2, T3, T5);
    zero_kernel<<<(BB_*65536)/256, blk, 0, stream>>>(S0, BB_*65536);

    // chan_att(x): gram(P0, x)
    gram128_kernel<<<gGram, blk, 0, stream>>>(W0, x, part);
    reduce16_kernel<<<(BB_*65536)/256, blk, 0, stream>>>(part, S1);
    att_acc_kernel<<<BB_*CC_, blk, 0, stream>>>(S1, S0);
    // chan_att(L1)
    rowsoftmax_kernel<false><<<BB_*CC_, blk, 0, stream>>>(W1, nullptr, W0);
    gram128_kernel<<<gGram, blk, 0, stream>>>(W0, W1, part);
    reduce16_kernel<<<(BB_*65536)/256, blk, 0, stream>>>(part, S1);
    att_acc_kernel<<<BB_*CC_, blk, 0, stream>>>(S1, S0);
    // chan_att(L2)
    rowsoftmax_kernel<false><<<BB_*CC_, blk, 0, stream>>>(W2, nullptr, W0);
    gram128_kernel<<<gGram, blk, 0, stream>>>(W0, W2, part);
    reduce16_kernel<<<(BB_*65536)/256, blk, 0, stream>>>(part, S1);
    att_acc_kernel<<<BB_*CC_, blk, 0, stream>>>(S1, S0);

    // keys = rowsoftmax(Wk@x + bk) -> W1 ; KX = keys @ x^T -> S1
    gemm128_kernel<0,0><<<gGemm, blk, 0, stream>>>(Wk, bk, x, W1, nullptr);
    rowsoftmax_kernel<false><<<BB_*CC_, blk, 0, stream>>>(W1, nullptr, W1);
    gram128_kernel<<<gGram, blk, 0, stream>>>(W1, x, part);
    reduce16_kernel<<<(BB_*65536)/256, blk, 0, stream>>>(part, S1);

    // queries = colsoftmax(Wq@x + bq) -> W2
    gemm128_kernel<0,0><<<gGemm, blk, 0, stream>>>(Wq, bq, x, W2, nullptr);
    colsoftmax_kernel<<<BB_*64, blk, 0, stream>>>(W2);

    // ctx[b,k,v] = sum_c KX[b,k,c]*Wv[v,c] + bv[v]   -> S2
    nt256_kernel<1,0,0><<<gNT, blk, 0, stream>>>(S1, Wv, bv, nullptr, nullptr, S2);
    // Mb[b,m,k] = wdw0[m]*(sum_v Wr[m,v]*ctx[b,k,v]) + wdw1[m]*att[b,k,m]  -> S1
    nt256_kernel<0,1,1><<<gNT, blk, 0, stream>>>(Wr, S2, nullptr, S0, wdw, S1);

    // out = Mb @ queries + wdw0*br
    gemm128_kernel<1,1><<<gGemm, blk, 0, stream>>>(S1, br, W2, out, wdw);
}

// Round 3
// 260.978 us; speedup vs baseline: 3.6743x; 2.2737x over previous
//
#include <hip/hip_runtime.h>
#include <math.h>

#define BB_ 8
#define CC_ 256
#define HWSZ 4096            // 64*64
#define CHW (CC_*HWSZ)       // 1,048,576
#define BCHW (BB_*CHW)       // 8,388,608

typedef __attribute__((ext_vector_type(8))) short short8v;
typedef __attribute__((ext_vector_type(4))) float f32x4;

struct Taps5 { float t[5]; };

__device__ inline ushort f2b(float f){
    uint u = __float_as_uint(f);
    u += 0x7FFF + ((u >> 16) & 1);
    return (ushort)(u >> 16);
}
__device__ inline float b2f(ushort u){
    return __uint_as_float(((uint)u) << 16);
}

// ---------------- prep: x f32 -> xb bf16 (natural) + xTb bf16 (transposed [hw][c]) ----------------
__global__ __launch_bounds__(256) void prepx_kernel(const float* __restrict__ x,
        ushort* __restrict__ xb, ushort* __restrict__ xTb){
    const int b = blockIdx.z, c0 = blockIdx.y*64, h0 = blockIdx.x*64;
    const float* xp = x + (size_t)b*CHW;
    __shared__ float T[64][65];
    const int tid = threadIdx.x;
    const int cl = tid >> 4;            // 0..15
    const int hl = (tid & 15) * 4;      // 0..60
    #pragma unroll
    for (int p = 0; p < 4; ++p){
        int c = c0 + p*16 + cl;
        float4 v = *(const float4*)&xp[(size_t)c*4096 + h0 + hl];
        ushort4 u; u.x = f2b(v.x); u.y = f2b(v.y); u.z = f2b(v.z); u.w = f2b(v.w);
        *(ushort4*)&xb[(size_t)b*CHW + (size_t)c*4096 + h0 + hl] = u;
        T[p*16+cl][hl+0] = v.x;
        T[p*16+cl][hl+1] = v.y;
        T[p*16+cl][hl+2] = v.z;
        T[p*16+cl][hl+3] = v.w;
    }
    __syncthreads();
    const int hr = tid >> 2;            // 0..63
    const int cs = (tid & 3) * 16;      // 0..48
    short8v o0, o1;
    #pragma unroll
    for (int i = 0; i < 8; ++i) o0[i] = (short)f2b(T[cs+i][hr]);
    #pragma unroll
    for (int i = 0; i < 8; ++i) o1[i] = (short)f2b(T[cs+8+i][hr]);
    ushort* dst = xTb + (size_t)b*CHW + (size_t)(h0+hr)*256 + c0 + cs;
    *(short8v*)dst = o0;
    *(short8v*)(dst+8) = o1;
}

// ---------------- fused pyramid + softmax(x), per (b,c) plane ----------------
// writes P0b = softmax(x) bf16, L1b = x-G1 bf16, L2b = G1-G2 bf16
__global__ __launch_bounds__(256) void plane_kernel(const float* __restrict__ x,
        ushort* __restrict__ P0, ushort* __restrict__ L1o, ushort* __restrict__ L2o,
        Taps5 t3, Taps5 t5){
    const size_t base = (size_t)blockIdx.x * HWSZ;
    const int tid = threadIdx.x;
    const int r  = tid >> 2;           // 0..63
    const int cq = (tid & 3) * 16;     // 0,16,32,48
    __shared__ float X[64*65];
    __shared__ float T[64*65];
    __shared__ float G[64*65];
    #pragma unroll
    for (int i = 0; i < 4; ++i){
        float4 v = *reinterpret_cast<const float4*>(&x[base + r*64 + cq + i*4]);
        X[r*65 + cq + i*4 + 0] = v.x;
        X[r*65 + cq + i*4 + 1] = v.y;
        X[r*65 + cq + i*4 + 2] = v.z;
        X[r*65 + cq + i*4 + 3] = v.w;
    }
    __syncthreads();
    #pragma unroll
    for (int j = 0; j < 16; ++j){
        int c = cq + j;
        float l = (c > 0)  ? X[r*65 + c - 1] : 0.f;
        float m = X[r*65 + c];
        float rr = (c < 63) ? X[r*65 + c + 1] : 0.f;
        T[r*65 + c] = t3.t[0]*l + t3.t[1]*m + t3.t[2]*rr;
    }
    __syncthreads();
    #pragma unroll
    for (int j = 0; j < 16; ++j){
        int c = cq + j;
        float u = (r > 0)  ? T[(r-1)*65 + c] : 0.f;
        float m = T[r*65 + c];
        float d = (r < 63) ? T[(r+1)*65 + c] : 0.f;
        G[r*65 + c] = t3.t[0]*u + t3.t[1]*m + t3.t[2]*d;
    }
    __syncthreads();
    #pragma unroll
    for (int j = 0; j < 16; ++j){
        int c = cq + j;
        float acc = 0.f;
        #pragma unroll
        for (int d = -2; d <= 2; ++d){
            int cc = c + d;
            float v = (cc >= 0 && cc < 64) ? G[r*65 + cc] : 0.f;
            acc += t5.t[d+2]*v;
        }
        T[r*65 + c] = acc;
    }
    __syncthreads();
    float v0[16], v1[16], v2[16];
    float mx = -INFINITY;
    #pragma unroll
    for (int j = 0; j < 16; ++j){
        int c = cq + j;
        float g2 = 0.f;
        #pragma unroll
        for (int d = -2; d <= 2; ++d){
            int rr2 = r + d;
            float v = (rr2 >= 0 && rr2 < 64) ? T[rr2*65 + c] : 0.f;
            g2 += t5.t[d+2]*v;
        }
        float xv = X[r*65 + c];
        float g1 = G[r*65 + c];
        v0[j] = xv;
        v1[j] = xv - g1;
        v2[j] = g1 - g2;
        mx = fmaxf(mx, xv);
    }
    #pragma unroll
    for (int off = 32; off > 0; off >>= 1) mx = fmaxf(mx, __shfl_xor(mx, off));
    __shared__ float redm[4], reds[4];
    int wid = tid >> 6, lane = tid & 63;
    if (lane == 0) redm[wid] = mx;
    __syncthreads();
    mx = fmaxf(fmaxf(redm[0], redm[1]), fmaxf(redm[2], redm[3]));
    float s = 0.f;
    #pragma unroll
    for (int j = 0; j < 16; ++j){ v0[j] = expf(v0[j] - mx); s += v0[j]; }
    #pragma unroll
    for (int off = 32; off > 0; off >>= 1) s += __shfl_xor(s, off);
    if (lane == 0) reds[wid] = s;
    __syncthreads();
    s = reds[0] + reds[1] + reds[2] + reds[3];
    float inv = 1.f / s;
    size_t o = base + r*64 + cq;
    short8v p0, p1, a0, a1, b0, b1;
    #pragma unroll
    for (int i = 0; i < 8; ++i){
        p0[i] = (short)f2b(v0[i]*inv);   p1[i] = (short)f2b(v0[8+i]*inv);
        a0[i] = (short)f2b(v1[i]);       a1[i] = (short)f2b(v1[8+i]);
        b0[i] = (short)f2b(v2[i]);       b1[i] = (short)f2b(v2[8+i]);
    }
    *(short8v*)&P0[o] = p0;  *(short8v*)&P0[o+8] = p1;
    *(short8v*)&L1o[o] = a0; *(short8v*)&L1o[o+8] = a1;
    *(short8v*)&L2o[o] = b0; *(short8v*)&L2o[o+8] = b1;
}

// ---------------- row softmax over HW (4096), bf16 or f32 input, bf16 out ----------------
template<bool BF16IN>
__global__ __launch_bounds__(256) void rowsm_kernel(const void* __restrict__ inp,
                                                    ushort* __restrict__ outp){
    const size_t base = (size_t)blockIdx.x * HWSZ + threadIdx.x * 16;
    const int tid = threadIdx.x;
    float v[16];
    if (BF16IN){
        const ushort* p = (const ushort*)inp + base;
        short8v a = *(const short8v*)p, b = *(const short8v*)(p+8);
        #pragma unroll
        for (int i = 0; i < 8; ++i){ v[i] = b2f((ushort)a[i]); v[8+i] = b2f((ushort)b[i]); }
    } else {
        const float* p = (const float*)inp + base;
        #pragma unroll
        for (int i = 0; i < 4; ++i){
            float4 f = *(const float4*)(p + i*4);
            v[i*4+0]=f.x; v[i*4+1]=f.y; v[i*4+2]=f.z; v[i*4+3]=f.w;
        }
    }
    float m = v[0];
    #pragma unroll
    for (int i = 1; i < 16; ++i) m = fmaxf(m, v[i]);
    #pragma unroll
    for (int off = 32; off > 0; off >>= 1) m = fmaxf(m, __shfl_xor(m, off));
    __shared__ float redm[4], reds[4];
    int wid = tid >> 6, lane = tid & 63;
    if (lane == 0) redm[wid] = m;
    __syncthreads();
    m = fmaxf(fmaxf(redm[0], redm[1]), fmaxf(redm[2], redm[3]));
    float s = 0.f;
    #pragma unroll
    for (int i = 0; i < 16; ++i){ v[i] = expf(v[i] - m); s += v[i]; }
    #pragma unroll
    for (int off = 32; off > 0; off >>= 1) s += __shfl_xor(s, off);
    if (lane == 0) reds[wid] = s;
    __syncthreads();
    s = reds[0] + reds[1] + reds[2] + reds[3];
    float inv = 1.f / s;
    short8v o0, o1;
    #pragma unroll
    for (int i = 0; i < 8; ++i){ o0[i] = (short)f2b(v[i]*inv); o1[i] = (short)f2b(v[8+i]*inv); }
    ushort* op = outp + base;
    *(short8v*)op = o0; *(short8v*)(op+8) = o1;
}

// ---------------- MFMA NT GEMM: C[m,n] = sum_k A[m,k]*B[n,k] (+epi) ----------------
// 128x128 tile, 4 waves of 64x64, bf16 operands, f32 out.
// z = bb*KC + kc; EPI: 0 none, 1 +bias[m], 2 +bias[n], 3 +wdw[2m]*bias[m]
template<int EPI, int KC>
__global__ __launch_bounds__(256) void mfma_nt(
        const ushort* __restrict__ A, size_t Abstride, int lda,
        const ushort* __restrict__ B, size_t Bbstride, int ldb,
        float* __restrict__ C, size_t Czstride, int ldc,
        int Kchunk, const float* __restrict__ bias, const float* __restrict__ wdw){
    __shared__ ushort As[128*64];
    __shared__ ushort Bs[128*64];
    const int z = blockIdx.z;
    const int bb = z / KC;
    const int kc = z % KC;
    const int m0 = blockIdx.y * 128, n0 = blockIdx.x * 128;
    const int kbeg = kc * Kchunk;
    const int tid = threadIdx.x;
    const int l = tid & 63, w = tid >> 6;
    const int wm = (w >> 1) * 64, wn = (w & 1) * 64;
    const int srow = tid >> 1, sseg = (tid & 1) * 32;
    const int sbase = srow*64 + sseg;
    const int swr = (srow & 7) << 3;
    const ushort* Ag0 = A + (size_t)bb*Abstride + (size_t)(m0+srow)*lda + kbeg + sseg;
    const ushort* Bg0 = B + (size_t)bb*Bbstride + (size_t)(n0+srow)*ldb + kbeg + sseg;
    int rabase[4], raswz[4], rbbase[4], rbswz[4];
    #pragma unroll
    for (int f = 0; f < 4; ++f){
        int ra = wm + f*16 + (l & 15);
        int rb = wn + f*16 + (l & 15);
        rabase[f] = ra*64 + (l>>4)*8;  raswz[f] = (ra & 7) << 3;
        rbbase[f] = rb*64 + (l>>4)*8;  rbswz[f] = (rb & 7) << 3;
    }
    f32x4 acc[4][4] = {};
    const int ktiles = Kchunk >> 6;
    for (int kt = 0; kt < ktiles; ++kt){
        const ushort* Ag = Ag0 + kt*64;
        const ushort* Bg = Bg0 + kt*64;
        #pragma unroll
        for (int i = 0; i < 4; ++i){
            short8v va = *(const short8v*)(Ag + i*8);
            short8v vb = *(const short8v*)(Bg + i*8);
            int idx = (sbase + i*8) ^ swr;
            *(short8v*)&As[idx] = va;
            *(short8v*)&Bs[idx] = vb;
        }
        __syncthreads();
        #pragma unroll
        for (int ks = 0; ks < 2; ++ks){
            short8v af[4], bf[4];
            #pragma unroll
            for (int f = 0; f < 4; ++f){
                af[f] = *(const short8v*)&As[(rabase[f] + ks*32) ^ raswz[f]];
                bf[f] = *(const short8v*)&Bs[(rbbase[f] + ks*32) ^ rbswz[f]];
            }
            #pragma unroll
            for (int fi = 0; fi < 4; ++fi)
                #pragma unroll
                for (int fj = 0; fj < 4; ++fj)
                    acc[fi][fj] = __builtin_amdgcn_mfma_f32_16x16x32_bf16(af[fi], bf[fj], acc[fi][fj], 0, 0, 0);
        }
        __syncthreads();
    }
    const int erow = (l >> 4) * 4, ecol = l & 15;
    #pragma unroll
    for (int fi = 0; fi < 4; ++fi){
        #pragma unroll
        for (int r = 0; r < 4; ++r){
            const int m = m0 + wm + fi*16 + erow + r;
            float madd = 0.f;
            if (EPI == 1) madd = bias[m];
            else if (EPI == 3) madd = wdw[2*m]*bias[m];
            #pragma unroll
            for (int fj = 0; fj < 4; ++fj){
                const int n = n0 + wn + fj*16 + ecol;
                float v = acc[fi][fj][r];
                if (EPI == 1 || EPI == 3) v += madd;
                else if (EPI == 2) v += bias[n];
                C[(size_t)z*Czstride + (size_t)m*ldc + n] = v;
            }
        }
    }
}

// ---------------- fused: reduce 16 split-K partials + softmax over d + accumulate ----------------
template<bool INIT>
__global__ __launch_bounds__(256) void rsa_kernel(const float* __restrict__ part,
                                                  float* __restrict__ att){
    const int row = blockIdx.x;          // b*256 + c
    const int b = row >> 8;
    const int tid = threadIdx.x;
    const size_t base = ((size_t)(b*16) << 16) + (size_t)(row & 255)*256 + tid;
    float v = 0.f;
    #pragma unroll
    for (int kc = 0; kc < 16; ++kc) v += part[base + ((size_t)kc << 16)];
    float m = v;
    #pragma unroll
    for (int off = 32; off > 0; off >>= 1) m = fmaxf(m, __shfl_xor(m, off));
    __shared__ float redm[4], reds[4];
    int wid = tid >> 6, lane = tid & 63;
    if (lane == 0) redm[wid] = m;
    __syncthreads();
    m = fmaxf(fmaxf(redm[0], redm[1]), fmaxf(redm[2], redm[3]));
    float e = expf(v - m);
    float s = e;
    #pragma unroll
    for (int off = 32; off > 0; off >>= 1) s += __shfl_xor(s, off);
    if (lane == 0) reds[wid] = s;
    __syncthreads();
    s = reds[0] + reds[1] + reds[2] + reds[3];
    float r = e / s;
    size_t o = (size_t)row*256 + tid;
    if (INIT) att[o] = r; else att[o] += r;
}

// ---------------- plain reduce of 16 split-K partials (for KX) ----------------
__global__ void reduce16_kernel(const float* __restrict__ part, float* __restrict__ G){
    int i = blockIdx.x*256 + threadIdx.x;    // over B*65536
    if (i >= BB_*65536) return;
    int b = i >> 16; int r = i & 65535;
    float s = 0.f;
    #pragma unroll
    for (int kc = 0; kc < 16; ++kc) s += part[(((size_t)(b*16 + kc)) << 16) + r];
    G[i] = s;
}

// ---------------- softmax over last dim (256) of qT_pre, out bf16 ----------------
__global__ __launch_bounds__(256) void qsm_kernel(const float* __restrict__ in,
                                                  ushort* __restrict__ outb){
    const size_t base = (size_t)blockIdx.x * 256;
    const int tid = threadIdx.x;
    float v = in[base + tid];
    float m = v;
    #pragma unroll
    for (int off = 32; off > 0; off >>= 1) m = fmaxf(m, __shfl_xor(m, off));
    __shared__ float redm[4], reds[4];
    int wid = tid >> 6, lane = tid & 63;
    if (lane == 0) redm[wid] = m;
    __syncthreads();
    m = fmaxf(fmaxf(redm[0], redm[1]), fmaxf(redm[2], redm[3]));
    float e = expf(v - m);
    float s = e;
    #pragma unroll
    for (int off = 32; off > 0; off >>= 1) s += __shfl_xor(s, off);
    if (lane == 0) reds[wid] = s;
    __syncthreads();
    s = reds[0] + reds[1] + reds[2] + reds[3];
    outb[base + tid] = f2b(e / s);
}

// ---------------- f32 -> bf16 convert ----------------
__global__ void cvt_kernel(const float* __restrict__ in, ushort* __restrict__ o, int n4){
    int i = blockIdx.x*256 + threadIdx.x;
    if (i < n4){
        float4 v = *(const float4*)&in[i*4];
        ushort4 u; u.x = f2b(v.x); u.y = f2b(v.y); u.z = f2b(v.z); u.w = f2b(v.w);
        *(ushort4*)&o[i*4] = u;
    }
}

// ---------------- small NT gemm 256x256x256 per-batch (f32 VALU) ----------------
// C[b,m,n] = sum_l Aeff[m,l]*Beff[n,l] + epi
// EPI 0: + bias[n] ; EPI 1: wdw[2m]*acc + wdw[2m+1]*att[b,n,m]
template<int ABATCH, int BBATCH, int EPI>
__global__ __launch_bounds__(256) void nt256_kernel(const float* __restrict__ A,
        const float* __restrict__ B, const float* __restrict__ bias,
        const float* __restrict__ att, const float* __restrict__ wdw,
        float* __restrict__ C){
    const int bb = blockIdx.z;
    const int m0 = blockIdx.y * 64, n0 = blockIdx.x * 64;
    const float* Ab = ABATCH ? A + (size_t)bb*65536 : A;
    const float* Bb = BBATCH ? B + (size_t)bb*65536 : B;
    __shared__ float Au[32*68];
    __shared__ float Bu[32*68];
    const int tid = threadIdx.x;
    const int tx = tid & 15, ty = tid >> 4;
    const int row = tid >> 2, loff = (tid & 3) * 8;
    float acc[4][4] = {};
    for (int k0 = 0; k0 < 256; k0 += 32){
        float4 a0 = *(const float4*)&Ab[(size_t)(m0+row)*256 + k0 + loff];
        float4 a1 = *(const float4*)&Ab[(size_t)(m0+row)*256 + k0 + loff + 4];
        float4 b0 = *(const float4*)&Bb[(size_t)(n0+row)*256 + k0 + loff];
        float4 b1 = *(const float4*)&Bb[(size_t)(n0+row)*256 + k0 + loff + 4];
        Au[(loff+0)*68 + row] = a0.x;
        Au[(loff+1)*68 + row] = a0.y;
        Au[(loff+2)*68 + row] = a0.z;
        Au[(loff+3)*68 + row] = a0.w;
        Au[(loff+4)*68 + row] = a1.x;
        Au[(loff+5)*68 + row] = a1.y;
        Au[(loff+6)*68 + row] = a1.z;
        Au[(loff+7)*68 + row] = a1.w;
        Bu[(loff+0)*68 + row] = b0.x;
        Bu[(loff+1)*68 + row] = b0.y;
        Bu[(loff+2)*68 + row] = b0.z;
        Bu[(loff+3)*68 + row] = b0.w;
        Bu[(loff+4)*68 + row] = b1.x;
        Bu[(loff+5)*68 + row] = b1.y;
        Bu[(loff+6)*68 + row] = b1.z;
        Bu[(loff+7)*68 + row] = b1.w;
        __syncthreads();
        #pragma unroll
        for (int kk = 0; kk < 32; ++kk){
            float4 av = *(const float4*)&Au[kk*68 + ty*4];
            float4 bv = *(const float4*)&Bu[kk*68 + tx*4];
            float aa[4] = {av.x, av.y, av.z, av.w};
            float bb2[4] = {bv.x, bv.y, bv.z, bv.w};
            #pragma unroll
            for (int i = 0; i < 4; ++i)
                #pragma unroll
                for (int j = 0; j < 4; ++j)
                    acc[i][j] += aa[i]*bb2[j];
        }
        __syncthreads();
    }
    #pragma unroll
    for (int i = 0; i < 4; ++i){
        int m = m0 + ty*4 + i;
        float4 wv;
        float* wp = &wv.x;
        #pragma unroll
        for (int j = 0; j < 4; ++j){
            int n = n0 + tx*4 + j;
            float v = acc[i][j];
            if (EPI == 0) v += bias[n];
            else v = wdw[2*m]*v + wdw[2*m+1]*att[(size_t)bb*65536 + (size_t)n*256 + m];
            wp[j] = v;
        }
        *(float4*)&C[(size_t)bb*65536 + (size_t)m*256 + n0 + tx*4] = wv;
    }
}

// ---------------- host ----------------
extern "C" void kernel_launch(void* const* d_in, const int* in_sizes, int n_in,
                              void* d_out, int out_size, void* d_ws, size_t ws_size,
                              hipStream_t stream){
    const float* x   = (const float*)d_in[0];
    const float* Wk  = (const float*)d_in[1];
    const float* bk  = (const float*)d_in[2];
    const float* Wq  = (const float*)d_in[3];
    const float* bq  = (const float*)d_in[4];
    const float* Wv  = (const float*)d_in[5];
    const float* bv  = (const float*)d_in[6];
    const float* Wr  = (const float*)d_in[7];
    const float* br  = (const float*)d_in[8];
    const float* wdw = (const float*)d_in[9];
    float* out = (float*)d_out;

    char* w = (char*)d_ws;
    ushort* xb   = (ushort*)w;  w += (size_t)BCHW*2;
    ushort* xTb  = (ushort*)w;  w += (size_t)BCHW*2;
    ushort* Pbuf = (ushort*)w;  w += (size_t)BCHW*2;   // P0/P1/P2/keysb/qTb
    ushort* L1b  = (ushort*)w;                          // F region start
    ushort* L2b  = L1b + (size_t)BCHW;
    float*  Fre  = (float*)L1b;                         // keys_pre / qT_pre (f32, BCHW)
    w += (size_t)BCHW*2*2;
    float* att  = (float*)w; w += (size_t)BB_*65536*4;
    float* KX   = (float*)w; w += (size_t)BB_*65536*4;
    float* ctx  = (float*)w; w += (size_t)BB_*65536*4;
    float* Mb   = (float*)w; w += (size_t)BB_*65536*4;
    ushort* Mbb = (ushort*)w; w += (size_t)BB_*65536*2;
    ushort* Wkb = (ushort*)w; w += 65536*2;
    ushort* Wqb = (ushort*)w; w += 65536*2;
    float* part = out;    // 8*16*65536 f32 == out_size exactly

    Taps5 T3{}, T5{};
    {
        double g[5], s;
        s = 0; for (int i = 0; i < 3; ++i){ double d = i - 1.0; g[i] = exp(-d*d/(2.0*1.6*1.6)); s += g[i]; }
        for (int i = 0; i < 3; ++i) T3.t[i] = (float)(g[i]/s);
        double sig = 1.6 * pow(2.0, 1.0/3.0);
        s = 0; for (int i = 0; i < 5; ++i){ double d = i - 2.0; g[i] = exp(-d*d/(2.0*sig*sig)); s += g[i]; }
        for (int i = 0; i < 5; ++i) T5.t[i] = (float)(g[i]/s);
    }

    const dim3 blk(256);
    const dim3 gGram(2, 2, 128);      // 128x128 tiles over 256x256, KC=16 split-K
    const dim3 gKeys(32, 2, 8);       // M=256, N=4096
    const dim3 gQuer(2, 32, 8);       // M=4096, N=256
    const dim3 gNT(4, 4, 8);

    // prep + pyramid
    prepx_kernel<<<dim3(64,4,8), blk, 0, stream>>>(x, xb, xTb);
    plane_kernel<<<BB_*CC_, blk, 0, stream>>>(x, Pbuf, L1b, L2b, T3, T5);
    cvt_kernel<<<64, blk, 0, stream>>>(Wk, Wkb, 16384);
    cvt_kernel<<<64, blk, 0, stream>>>(Wq, Wqb, 16384);

    // chan_att(x): gram(P0, x)
    mfma_nt<0,16><<<gGram, blk, 0, stream>>>(Pbuf, CHW, 4096, xb, CHW, 4096,
                                             part, 65536, 256, 256, nullptr, nullptr);
    rsa_kernel<true><<<BB_*CC_, blk, 0, stream>>>(part, att);
    // chan_att(L1)
    rowsm_kernel<true><<<BB_*CC_, blk, 0, stream>>>(L1b, Pbuf);
    mfma_nt<0,16><<<gGram, blk, 0, stream>>>(Pbuf, CHW, 4096, L1b, CHW, 4096,
                                             part, 65536, 256, 256, nullptr, nullptr);
    rsa_kernel<false><<<BB_*CC_, blk, 0, stream>>>(part, att);
    // chan_att(L2)
    rowsm_kernel<true><<<BB_*CC_, blk, 0, stream>>>(L2b, Pbuf);
    mfma_nt<0,16><<<gGram, blk, 0, stream>>>(Pbuf, CHW, 4096, L2b, CHW, 4096,
                                             part, 65536, 256, 256, nullptr, nullptr);
    rsa_kernel<false><<<BB_*CC_, blk, 0, stream>>>(part, att);

    // keys = rowsoftmax(Wk@x + bk):  keys_pre = NT(Wkb, xTb) + bk  (f32, into F region)
    mfma_nt<1,1><<<gKeys, blk, 0, stream>>>(Wkb, 0, 256, xTb, CHW, 256,
                                            Fre, CHW, 4096, 256, bk, nullptr);
    rowsm_kernel<false><<<BB_*CC_, blk, 0, stream>>>(Fre, Pbuf);   // keysb -> Pbuf
    // KX = keys @ x^T
    mfma_nt<0,16><<<gGram, blk, 0, stream>>>(Pbuf, CHW, 4096, xb, CHW, 4096,
                                             part, 65536, 256, 256, nullptr, nullptr);
    reduce16_kernel<<<(BB_*65536)/256, blk, 0, stream>>>(part, KX);

    // queriesT = colsoftmax(Wq@x + bq):  qT_pre = NT(xTb, Wqb) + bq[n]  (f32, F region)
    mfma_nt<2,1><<<gQuer, blk, 0, stream>>>(xTb, CHW, 256, Wqb, 0, 256,
                                            Fre, CHW, 256, 256, bq, nullptr);
    qsm_kernel<<<BB_*HWSZ, blk, 0, stream>>>(Fre, Pbuf);            // qTb -> Pbuf

    // ctx[b,k,v] = sum_c KX[b,k,c]*Wv[v,c] + bv[v]
    nt256_kernel<1,0,0><<<gNT, blk, 0, stream>>>(KX, Wv, bv, nullptr, nullptr, ctx);
    // Mb[b,m,k] = wdw0[m]*(sum_v Wr[m,v]*ctx[b,k,v]) + wdw1[m]*att[b,k,m]
    nt256_kernel<0,1,1><<<gNT, blk, 0, stream>>>(Wr, ctx, nullptr, att, wdw, Mb);
    cvt_kernel<<<512, blk, 0, stream>>>(Mb, Mbb, 131072);

    // out = Mb @ qT^T + wdw0*br  :  NT(Mbb, qTb)
    mfma_nt<3,1><<<gKeys, blk, 0, stream>>>(Mbb, 65536, 256, Pbuf, CHW, 256,
                                            out, CHW, 4096, 256, br, wdw);
}

// Round 4
// 214.787 us; speedup vs baseline: 4.4645x; 1.2151x over previous
//
#include <hip/hip_runtime.h>
#include <math.h>

#define BB_ 8
#define CC_ 256
#define HWSZ 4096            // 64*64
#define CHW (CC_*HWSZ)       // 1,048,576
#define BCHW (BB_*CHW)       // 8,388,608

typedef __attribute__((ext_vector_type(8))) short short8v;
typedef __attribute__((ext_vector_type(4))) float f32x4;

struct Taps5 { float t[5]; };

__device__ inline ushort f2b(float f){
    uint u = __float_as_uint(f);
    u += 0x7FFF + ((u >> 16) & 1);
    return (ushort)(u >> 16);
}
__device__ inline float b2f(ushort u){
    return __uint_as_float(((uint)u) << 16);
}

// ---------------- prep: x f32 -> xb bf16 (natural, into S[0]) + xTb bf16 ([hw][c]) ----------------
__global__ __launch_bounds__(256) void prepx_kernel(const float* __restrict__ x,
        ushort* __restrict__ xb, ushort* __restrict__ xTb){
    const int b = blockIdx.z, c0 = blockIdx.y*64, h0 = blockIdx.x*64;
    const float* xp = x + (size_t)b*CHW;
    __shared__ float T[64][65];
    const int tid = threadIdx.x;
    const int cl = tid >> 4;            // 0..15
    const int hl = (tid & 15) * 4;      // 0..60
    #pragma unroll
    for (int p = 0; p < 4; ++p){
        int c = c0 + p*16 + cl;
        float4 v = *(const float4*)&xp[(size_t)c*4096 + h0 + hl];
        ushort4 u; u.x = f2b(v.x); u.y = f2b(v.y); u.z = f2b(v.z); u.w = f2b(v.w);
        *(ushort4*)&xb[(size_t)b*CHW + (size_t)c*4096 + h0 + hl] = u;
        T[p*16+cl][hl+0] = v.x;
        T[p*16+cl][hl+1] = v.y;
        T[p*16+cl][hl+2] = v.z;
        T[p*16+cl][hl+3] = v.w;
    }
    __syncthreads();
    const int hr = tid >> 2;            // 0..63
    const int cs = (tid & 3) * 16;      // 0..48
    short8v o0, o1;
    #pragma unroll
    for (int i = 0; i < 8; ++i) o0[i] = (short)f2b(T[cs+i][hr]);
    #pragma unroll
    for (int i = 0; i < 8; ++i) o1[i] = (short)f2b(T[cs+8+i][hr]);
    ushort* dst = xTb + (size_t)b*CHW + (size_t)(h0+hr)*256 + c0 + cs;
    *(short8v*)dst = o0;
    *(short8v*)(dst+8) = o1;
}

// ---------------- fused pyramid + 3 plane softmaxes, per (b,c) plane ----------------
// P[g] = softmax(L_g) bf16 (g=0:x, 1:x-G1, 2:G1-G2); S1=L1 raw bf16, S2=L2 raw bf16
__global__ __launch_bounds__(256) void plane5_kernel(const float* __restrict__ x,
        ushort* __restrict__ P, ushort* __restrict__ S1, ushort* __restrict__ S2,
        Taps5 t3, Taps5 t5){
    const size_t base = (size_t)blockIdx.x * HWSZ;
    const int tid = threadIdx.x;
    const int r  = tid >> 2;           // 0..63
    const int cq = (tid & 3) * 16;     // 0,16,32,48
    __shared__ float X[64*65];
    __shared__ float T[64*65];
    __shared__ float G[64*65];
    #pragma unroll
    for (int i = 0; i < 4; ++i){
        float4 v = *reinterpret_cast<const float4*>(&x[base + r*64 + cq + i*4]);
        X[r*65 + cq + i*4 + 0] = v.x;
        X[r*65 + cq + i*4 + 1] = v.y;
        X[r*65 + cq + i*4 + 2] = v.z;
        X[r*65 + cq + i*4 + 3] = v.w;
    }
    __syncthreads();
    #pragma unroll
    for (int j = 0; j < 16; ++j){
        int c = cq + j;
        float l = (c > 0)  ? X[r*65 + c - 1] : 0.f;
        float m = X[r*65 + c];
        float rr = (c < 63) ? X[r*65 + c + 1] : 0.f;
        T[r*65 + c] = t3.t[0]*l + t3.t[1]*m + t3.t[2]*rr;
    }
    __syncthreads();
    #pragma unroll
    for (int j = 0; j < 16; ++j){
        int c = cq + j;
        float u = (r > 0)  ? T[(r-1)*65 + c] : 0.f;
        float m = T[r*65 + c];
        float d = (r < 63) ? T[(r+1)*65 + c] : 0.f;
        G[r*65 + c] = t3.t[0]*u + t3.t[1]*m + t3.t[2]*d;
    }
    __syncthreads();
    #pragma unroll
    for (int j = 0; j < 16; ++j){
        int c = cq + j;
        float acc = 0.f;
        #pragma unroll
        for (int d = -2; d <= 2; ++d){
            int cc = c + d;
            float v = (cc >= 0 && cc < 64) ? G[r*65 + cc] : 0.f;
            acc += t5.t[d+2]*v;
        }
        T[r*65 + c] = acc;
    }
    __syncthreads();
    float vv[3][16];
    #pragma unroll
    for (int j = 0; j < 16; ++j){
        int c = cq + j;
        float g2 = 0.f;
        #pragma unroll
        for (int d = -2; d <= 2; ++d){
            int rr2 = r + d;
            float v = (rr2 >= 0 && rr2 < 64) ? T[rr2*65 + c] : 0.f;
            g2 += t5.t[d+2]*v;
        }
        float xv = X[r*65 + c];
        float g1 = G[r*65 + c];
        vv[0][j] = xv;
        vv[1][j] = xv - g1;
        vv[2][j] = g1 - g2;
    }
    const size_t o = base + r*64 + cq;
    // write raw L1, L2 (bf16) before softmax clobbers vv
    {
        short8v a0, a1, b0, b1;
        #pragma unroll
        for (int i = 0; i < 8; ++i){
            a0[i] = (short)f2b(vv[1][i]);   a1[i] = (short)f2b(vv[1][8+i]);
            b0[i] = (short)f2b(vv[2][i]);   b1[i] = (short)f2b(vv[2][8+i]);
        }
        *(short8v*)&S1[o] = a0; *(short8v*)&S1[o+8] = a1;
        *(short8v*)&S2[o] = b0; *(short8v*)&S2[o+8] = b1;
    }
    __shared__ float redm[3][4], reds[3][4];
    const int wid = tid >> 6, lane = tid & 63;
    #pragma unroll
    for (int g = 0; g < 3; ++g){
        float mx = vv[g][0];
        #pragma unroll
        for (int j = 1; j < 16; ++j) mx = fmaxf(mx, vv[g][j]);
        #pragma unroll
        for (int off = 32; off > 0; off >>= 1) mx = fmaxf(mx, __shfl_xor(mx, off));
        if (lane == 0) redm[g][wid] = mx;
        __syncthreads();
        mx = fmaxf(fmaxf(redm[g][0], redm[g][1]), fmaxf(redm[g][2], redm[g][3]));
        float s = 0.f;
        #pragma unroll
        for (int j = 0; j < 16; ++j){ vv[g][j] = expf(vv[g][j] - mx); s += vv[g][j]; }
        #pragma unroll
        for (int off = 32; off > 0; off >>= 1) s += __shfl_xor(s, off);
        if (lane == 0) reds[g][wid] = s;
        __syncthreads();
        s = reds[g][0] + reds[g][1] + reds[g][2] + reds[g][3];
        float inv = 1.f / s;
        short8v p0, p1;
        #pragma unroll
        for (int i = 0; i < 8; ++i){
            p0[i] = (short)f2b(vv[g][i]*inv);
            p1[i] = (short)f2b(vv[g][8+i]*inv);
        }
        ushort* Pg = P + (size_t)g*BCHW;
        *(short8v*)&Pg[o] = p0; *(short8v*)&Pg[o+8] = p1;
    }
}

// ---------------- row softmax over HW (4096), f32 in, bf16 out ----------------
__global__ __launch_bounds__(256) void rowsm_kernel(const float* __restrict__ inp,
                                                    ushort* __restrict__ outp){
    const size_t base = (size_t)blockIdx.x * HWSZ + threadIdx.x * 16;
    const int tid = threadIdx.x;
    float v[16];
    #pragma unroll
    for (int i = 0; i < 4; ++i){
        float4 f = *(const float4*)(inp + base + i*4);
        v[i*4+0]=f.x; v[i*4+1]=f.y; v[i*4+2]=f.z; v[i*4+3]=f.w;
    }
    float m = v[0];
    #pragma unroll
    for (int i = 1; i < 16; ++i) m = fmaxf(m, v[i]);
    #pragma unroll
    for (int off = 32; off > 0; off >>= 1) m = fmaxf(m, __shfl_xor(m, off));
    __shared__ float redm[4], reds[4];
    int wid = tid >> 6, lane = tid & 63;
    if (lane == 0) redm[wid] = m;
    __syncthreads();
    m = fmaxf(fmaxf(redm[0], redm[1]), fmaxf(redm[2], redm[3]));
    float s = 0.f;
    #pragma unroll
    for (int i = 0; i < 16; ++i){ v[i] = expf(v[i] - m); s += v[i]; }
    #pragma unroll
    for (int off = 32; off > 0; off >>= 1) s += __shfl_xor(s, off);
    if (lane == 0) reds[wid] = s;
    __syncthreads();
    s = reds[0] + reds[1] + reds[2] + reds[3];
    float inv = 1.f / s;
    short8v o0, o1;
    #pragma unroll
    for (int i = 0; i < 8; ++i){ o0[i] = (short)f2b(v[i]*inv); o1[i] = (short)f2b(v[8+i]*inv); }
    ushort* op = outp + base;
    *(short8v*)op = o0; *(short8v*)(op+8) = o1;
}

// ---------------- MFMA NT GEMM: C[m,n] = sum_k A[m,k]*B[n,k] (+epi) ----------------
// 128x128 tile, 4 waves of 64x64, bf16 operands, f32 out.
// z = bb*KC + kc; EPI: 0 none, 1 +bias[m], 3 +wdw[2m]*bias[m]
template<int EPI, int KC>
__global__ __launch_bounds__(256) void mfma_nt(
        const ushort* __restrict__ A, size_t Abstride, int lda,
        const ushort* __restrict__ B, size_t Bbstride, int ldb,
        float* __restrict__ C, size_t Czstride, int ldc,
        int Kchunk, const float* __restrict__ bias, const float* __restrict__ wdw){
    __shared__ ushort As[128*64];
    __shared__ ushort Bs[128*64];
    const int z = blockIdx.z;
    const int bb = z / KC;
    const int kc = z % KC;
    const int m0 = blockIdx.y * 128, n0 = blockIdx.x * 128;
    const int kbeg = kc * Kchunk;
    const int tid = threadIdx.x;
    const int l = tid & 63, w = tid >> 6;
    const int wm = (w >> 1) * 64, wn = (w & 1) * 64;
    const int srow = tid >> 1, sseg = (tid & 1) * 32;
    const int sbase = srow*64 + sseg;
    const int swr = (srow & 7) << 3;
    const ushort* Ag0 = A + (size_t)bb*Abstride + (size_t)(m0+srow)*lda + kbeg + sseg;
    const ushort* Bg0 = B + (size_t)bb*Bbstride + (size_t)(n0+srow)*ldb + kbeg + sseg;
    int rabase[4], raswz[4], rbbase[4], rbswz[4];
    #pragma unroll
    for (int f = 0; f < 4; ++f){
        int ra = wm + f*16 + (l & 15);
        int rb = wn + f*16 + (l & 15);
        rabase[f] = ra*64 + (l>>4)*8;  raswz[f] = (ra & 7) << 3;
        rbbase[f] = rb*64 + (l>>4)*8;  rbswz[f] = (rb & 7) << 3;
    }
    f32x4 acc[4][4] = {};
    const int ktiles = Kchunk >> 6;
    for (int kt = 0; kt < ktiles; ++kt){
        const ushort* Ag = Ag0 + kt*64;
        const ushort* Bg = Bg0 + kt*64;
        #pragma unroll
        for (int i = 0; i < 4; ++i){
            short8v va = *(const short8v*)(Ag + i*8);
            short8v vb = *(const short8v*)(Bg + i*8);
            int idx = (sbase + i*8) ^ swr;
            *(short8v*)&As[idx] = va;
            *(short8v*)&Bs[idx] = vb;
        }
        __syncthreads();
        #pragma unroll
        for (int ks = 0; ks < 2; ++ks){
            short8v af[4], bf[4];
            #pragma unroll
            for (int f = 0; f < 4; ++f){
                af[f] = *(const short8v*)&As[(rabase[f] + ks*32) ^ raswz[f]];
                bf[f] = *(const short8v*)&Bs[(rbbase[f] + ks*32) ^ rbswz[f]];
            }
            #pragma unroll
            for (int fi = 0; fi < 4; ++fi)
                #pragma unroll
                for (int fj = 0; fj < 4; ++fj)
                    acc[fi][fj] = __builtin_amdgcn_mfma_f32_16x16x32_bf16(af[fi], bf[fj], acc[fi][fj], 0, 0, 0);
        }
        __syncthreads();
    }
    const int erow = (l >> 4) * 4, ecol = l & 15;
    #pragma unroll
    for (int fi = 0; fi < 4; ++fi){
        #pragma unroll
        for (int r = 0; r < 4; ++r){
            const int m = m0 + wm + fi*16 + erow + r;
            float madd = 0.f;
            if (EPI == 1) madd = bias[m];
            else if (EPI == 3) madd = wdw[2*m]*bias[m];
            #pragma unroll
            for (int fj = 0; fj < 4; ++fj){
                const int n = n0 + wn + fj*16 + ecol;
                float v = acc[fi][fj][r];
                if (EPI == 1 || EPI == 3) v += madd;
                C[(size_t)z*Czstride + (size_t)m*ldc + n] = v;
            }
        }
    }
}

// ---------------- fused: 3x (reduce 8 partials + softmax(256)) + sum -> att ----------------
__global__ __launch_bounds__(256) void rsa3_kernel(const float* __restrict__ part,
                                                   float* __restrict__ att){
    const int row = blockIdx.x;      // b*256 + c
    const int b = row >> 8;
    const int tid = threadIdx.x;
    const int wid = tid >> 6, lane = tid & 63;
    __shared__ float redm[3][4], reds[3][4];
    float r[3];
    #pragma unroll
    for (int g = 0; g < 3; ++g){
        const size_t base = (((size_t)((g*8 + b)*8)) << 16) + (size_t)(row & 255)*256 + tid;
        float v = 0.f;
        #pragma unroll
        for (int kc = 0; kc < 8; ++kc) v += part[base + ((size_t)kc << 16)];
        float m = v;
        #pragma unroll
        for (int off = 32; off > 0; off >>= 1) m = fmaxf(m, __shfl_xor(m, off));
        if (lane == 0) redm[g][wid] = m;
        __syncthreads();
        m = fmaxf(fmaxf(redm[g][0], redm[g][1]), fmaxf(redm[g][2], redm[g][3]));
        float e = expf(v - m);
        float s = e;
        #pragma unroll
        for (int off = 32; off > 0; off >>= 1) s += __shfl_xor(s, off);
        if (lane == 0) reds[g][wid] = s;
        __syncthreads();
        s = reds[g][0] + reds[g][1] + reds[g][2] + reds[g][3];
        r[g] = e / s;
    }
    att[(size_t)row*256 + tid] = r[0] + r[1] + r[2];
}

// ---------------- reduce 8 split-K partials (KX) ----------------
__global__ void reduce8_kernel(const float* __restrict__ part, float* __restrict__ G){
    int i = blockIdx.x*256 + threadIdx.x;    // over B*65536
    if (i >= BB_*65536) return;
    int b = i >> 16; int r = i & 65535;
    float s = 0.f;
    #pragma unroll
    for (int kc = 0; kc < 8; ++kc) s += part[(((size_t)(b*8 + kc)) << 16) + r];
    G[i] = s;
}

// ---------------- queries GEMM + fused softmax over C: qT[b,hw,c] bf16 ----------------
// tile: 128 rows (hw) x 256 cols (c), K=256. 4 waves x (32 rows x 256 cols).
__global__ __launch_bounds__(256) void qgemm_sm(const ushort* __restrict__ xTb,
        const ushort* __restrict__ Wqb, const float* __restrict__ bq,
        ushort* __restrict__ qTb){
    __shared__ ushort As[128*64];
    __shared__ ushort Bs[256*64];
    const int b = blockIdx.z, m0 = blockIdx.x*128;
    const int tid = threadIdx.x, l = tid & 63, w = tid >> 6;
    const int wm = w*32;
    const int sArow = tid >> 1, sAseg = (tid & 1)*32;
    const int sAbase = sArow*64 + sAseg, sAswz = (sArow & 7) << 3;
    const int sBbase = tid*64, sBswz = (tid & 7) << 3;
    const ushort* Ag0 = xTb + (size_t)b*CHW + (size_t)(m0 + sArow)*256 + sAseg;
    const ushort* Bg0 = Wqb + (size_t)tid*256;
    f32x4 acc[2][16] = {};
    for (int kt = 0; kt < 4; ++kt){
        #pragma unroll
        for (int i = 0; i < 4; ++i){
            short8v va = *(const short8v*)(Ag0 + kt*64 + i*8);
            *(short8v*)&As[(sAbase + i*8) ^ sAswz] = va;
        }
        #pragma unroll
        for (int i = 0; i < 8; ++i){
            short8v vb = *(const short8v*)(Bg0 + kt*64 + i*8);
            *(short8v*)&Bs[(sBbase + i*8) ^ sBswz] = vb;
        }
        __syncthreads();
        #pragma unroll
        for (int ks = 0; ks < 2; ++ks){
            short8v af[2];
            #pragma unroll
            for (int fi = 0; fi < 2; ++fi){
                int ar = wm + fi*16 + (l & 15);
                af[fi] = *(const short8v*)&As[(ar*64 + ks*32 + (l>>4)*8) ^ ((ar & 7) << 3)];
            }
            #pragma unroll
            for (int fj = 0; fj < 16; ++fj){
                int br = fj*16 + (l & 15);
                short8v bf = *(const short8v*)&Bs[(br*64 + ks*32 + (l>>4)*8) ^ ((br & 7) << 3)];
                acc[0][fj] = __builtin_amdgcn_mfma_f32_16x16x32_bf16(af[0], bf, acc[0][fj], 0, 0, 0);
                acc[1][fj] = __builtin_amdgcn_mfma_f32_16x16x32_bf16(af[1], bf, acc[1][fj], 0, 0, 0);
            }
        }
        __syncthreads();
    }
    const int ecol = l & 15, egrp = l >> 4;
    float bqv[16];
    #pragma unroll
    for (int fj = 0; fj < 16; ++fj) bqv[fj] = bq[fj*16 + ecol];
    #pragma unroll
    for (int fi = 0; fi < 2; ++fi){
        #pragma unroll
        for (int r = 0; r < 4; ++r){
            const int m = m0 + wm + fi*16 + egrp*4 + r;
            float v[16];
            float mx = -INFINITY;
            #pragma unroll
            for (int fj = 0; fj < 16; ++fj){
                v[fj] = acc[fi][fj][r] + bqv[fj];
                mx = fmaxf(mx, v[fj]);
            }
            #pragma unroll
            for (int off = 1; off < 16; off <<= 1) mx = fmaxf(mx, __shfl_xor(mx, off));
            float s = 0.f;
            #pragma unroll
            for (int fj = 0; fj < 16; ++fj){ v[fj] = expf(v[fj] - mx); s += v[fj]; }
            #pragma unroll
            for (int off = 1; off < 16; off <<= 1) s += __shfl_xor(s, off);
            float inv = 1.f / s;
            ushort* op = qTb + (size_t)b*CHW + (size_t)m*256 + ecol;
            #pragma unroll
            for (int fj = 0; fj < 16; ++fj) op[fj*16] = f2b(v[fj]*inv);
        }
    }
}

// ---------------- small NT gemm 256x256x256 per-batch (f32 VALU) ----------------
// EPI 0: f32 out, + bias[n] ; EPI 1: bf16 out, wdw[2m]*acc + wdw[2m+1]*att[b,n,m]
template<int ABATCH, int BBATCH, int EPI>
__global__ __launch_bounds__(256) void nt256_kernel(const float* __restrict__ A,
        const float* __restrict__ B, const float* __restrict__ bias,
        const float* __restrict__ att, const float* __restrict__ wdw,
        void* __restrict__ Cout){
    const int bb = blockIdx.z;
    const int m0 = blockIdx.y * 64, n0 = blockIdx.x * 64;
    const float* Ab = ABATCH ? A + (size_t)bb*65536 : A;
    const float* Bb = BBATCH ? B + (size_t)bb*65536 : B;
    __shared__ float Au[32*68];
    __shared__ float Bu[32*68];
    const int tid = threadIdx.x;
    const int tx = tid & 15, ty = tid >> 4;
    const int row = tid >> 2, loff = (tid & 3) * 8;
    float acc[4][4] = {};
    for (int k0 = 0; k0 < 256; k0 += 32){
        float4 a0 = *(const float4*)&Ab[(size_t)(m0+row)*256 + k0 + loff];
        float4 a1 = *(const float4*)&Ab[(size_t)(m0+row)*256 + k0 + loff + 4];
        float4 b0 = *(const float4*)&Bb[(size_t)(n0+row)*256 + k0 + loff];
        float4 b1 = *(const float4*)&Bb[(size_t)(n0+row)*256 + k0 + loff + 4];
        Au[(loff+0)*68 + row] = a0.x;
        Au[(loff+1)*68 + row] = a0.y;
        Au[(loff+2)*68 + row] = a0.z;
        Au[(loff+3)*68 + row] = a0.w;
        Au[(loff+4)*68 + row] = a1.x;
        Au[(loff+5)*68 + row] = a1.y;
        Au[(loff+6)*68 + row] = a1.z;
        Au[(loff+7)*68 + row] = a1.w;
        Bu[(loff+0)*68 + row] = b0.x;
        Bu[(loff+1)*68 + row] = b0.y;
        Bu[(loff+2)*68 + row] = b0.z;
        Bu[(loff+3)*68 + row] = b0.w;
        Bu[(loff+4)*68 + row] = b1.x;
        Bu[(loff+5)*68 + row] = b1.y;
        Bu[(loff+6)*68 + row] = b1.z;
        Bu[(loff+7)*68 + row] = b1.w;
        __syncthreads();
        #pragma unroll
        for (int kk = 0; kk < 32; ++kk){
            float4 av = *(const float4*)&Au[kk*68 + ty*4];
            float4 bv = *(const float4*)&Bu[kk*68 + tx*4];
            float aa[4] = {av.x, av.y, av.z, av.w};
            float bb2[4] = {bv.x, bv.y, bv.z, bv.w};
            #pragma unroll
            for (int i = 0; i < 4; ++i)
                #pragma unroll
                for (int j = 0; j < 4; ++j)
                    acc[i][j] += aa[i]*bb2[j];
        }
        __syncthreads();
    }
    #pragma unroll
    for (int i = 0; i < 4; ++i){
        int m = m0 + ty*4 + i;
        if (EPI == 0){
            float4 wv;
            float* wp = &wv.x;
            #pragma unroll
            for (int j = 0; j < 4; ++j) wp[j] = acc[i][j] + bias[n0 + tx*4 + j];
            *(float4*)&((float*)Cout)[(size_t)bb*65536 + (size_t)m*256 + n0 + tx*4] = wv;
        } else {
            ushort4 uv;
            ushort* up = &uv.x;
            #pragma unroll
            for (int j = 0; j < 4; ++j){
                int n = n0 + tx*4 + j;
                float v = wdw[2*m]*acc[i][j] + wdw[2*m+1]*att[(size_t)bb*65536 + (size_t)n*256 + m];
                up[j] = f2b(v);
            }
            *(ushort4*)&((ushort*)Cout)[(size_t)bb*65536 + (size_t)m*256 + n0 + tx*4] = uv;
        }
    }
}

// ---------------- f32 -> bf16 convert ----------------
__global__ void cvt_kernel(const float* __restrict__ in, ushort* __restrict__ o, int n4){
    int i = blockIdx.x*256 + threadIdx.x;
    if (i < n4){
        float4 v = *(const float4*)&in[i*4];
        ushort4 u; u.x = f2b(v.x); u.y = f2b(v.y); u.z = f2b(v.z); u.w = f2b(v.w);
        *(ushort4*)&o[i*4] = u;
    }
}

// ---------------- host ----------------
extern "C" void kernel_launch(void* const* d_in, const int* in_sizes, int n_in,
                              void* d_out, int out_size, void* d_ws, size_t ws_size,
                              hipStream_t stream){
    const float* x   = (const float*)d_in[0];
    const float* Wk  = (const float*)d_in[1];
    const float* bk  = (const float*)d_in[2];
    const float* Wq  = (const float*)d_in[3];
    const float* bq  = (const float*)d_in[4];
    const float* Wv  = (const float*)d_in[5];
    const float* bv  = (const float*)d_in[6];
    const float* Wr  = (const float*)d_in[7];
    const float* br  = (const float*)d_in[8];
    const float* wdw = (const float*)d_in[9];
    float* out = (float*)d_out;

    char* w = (char*)d_ws;
    ushort* S    = (ushort*)w; w += (size_t)3*BCHW*2;        // S0=xb, S1=L1, S2=L2
    ushort* xTb  = (ushort*)w; w += (size_t)BCHW*2;
    ushort* P    = (ushort*)w; w += (size_t)3*BCHW*2;        // P0,P1,P2; later keysb/qTb
    float*  part = (float*)w;  w += (size_t)3*8*8*65536*4;   // 50.3MB; Fre & partK alias
    float*  att  = (float*)w;  w += (size_t)BB_*65536*4;
    float*  KX   = (float*)w;  w += (size_t)BB_*65536*4;
    float*  ctx  = (float*)w;  w += (size_t)BB_*65536*4;
    ushort* Mbb  = (ushort*)w; w += (size_t)BB_*65536*2;
    ushort* Wkb  = (ushort*)w; w += 65536*2;
    ushort* Wqb  = (ushort*)w; w += 65536*2;
    float*  Fre  = part;              // keys_pre f32 (alias, used after rsa3)
    float*  partK = part;             // keys-gram partials (alias, used after rowsm)
    ushort* keysb = P;                // reuse P after gram3
    ushort* qTb   = P + (size_t)BCHW;

    Taps5 T3{}, T5{};
    {
        double g[5], s;
        s = 0; for (int i = 0; i < 3; ++i){ double d = i - 1.0; g[i] = exp(-d*d/(2.0*1.6*1.6)); s += g[i]; }
        for (int i = 0; i < 3; ++i) T3.t[i] = (float)(g[i]/s);
        double sig = 1.6 * pow(2.0, 1.0/3.0);
        s = 0; for (int i = 0; i < 5; ++i){ double d = i - 2.0; g[i] = exp(-d*d/(2.0*sig*sig)); s += g[i]; }
        for (int i = 0; i < 5; ++i) T5.t[i] = (float)(g[i]/s);
    }

    const dim3 blk(256);

    // prep + pyramid (+3 plane softmaxes)
    prepx_kernel<<<dim3(64,4,8), blk, 0, stream>>>(x, S, xTb);
    plane5_kernel<<<BB_*CC_, blk, 0, stream>>>(x, P, S + (size_t)BCHW, S + (size_t)2*BCHW, T3, T5);
    cvt_kernel<<<64, blk, 0, stream>>>(Wk, Wkb, 16384);
    cvt_kernel<<<64, blk, 0, stream>>>(Wq, Wqb, 16384);

    // 3 chan-att grams in one launch: z = (g*8+b)*8 + kc, K-chunk 512
    mfma_nt<0,8><<<dim3(2,2,192), blk, 0, stream>>>(P, CHW, 4096, S, CHW, 4096,
                                                    part, 65536, 256, 512, nullptr, nullptr);
    rsa3_kernel<<<BB_*CC_, blk, 0, stream>>>(part, att);

    // keys = rowsoftmax(Wk@x + bk)
    mfma_nt<1,1><<<dim3(32,2,8), blk, 0, stream>>>(Wkb, 0, 256, xTb, CHW, 256,
                                                   Fre, CHW, 4096, 256, bk, nullptr);
    rowsm_kernel<<<BB_*CC_, blk, 0, stream>>>(Fre, keysb);
    // KX = keys @ x^T (split-K 8)
    mfma_nt<0,8><<<dim3(2,2,64), blk, 0, stream>>>(keysb, CHW, 4096, S, CHW, 4096,
                                                   partK, 65536, 256, 512, nullptr, nullptr);
    reduce8_kernel<<<(BB_*65536)/256, blk, 0, stream>>>(partK, KX);

    // queriesT = softmax over C fused into GEMM epilogue
    qgemm_sm<<<dim3(32,1,8), blk, 0, stream>>>(xTb, Wqb, bq, qTb);

    // ctx[b,k,v] = sum_c KX[b,k,c]*Wv[v,c] + bv[v]
    nt256_kernel<1,0,0><<<dim3(4,4,8), blk, 0, stream>>>(KX, Wv, bv, nullptr, nullptr, ctx);
    // Mbb[b,m,k] = bf16( wdw0[m]*(sum_v Wr[m,v]*ctx[b,k,v]) + wdw1[m]*att[b,k,m] )
    nt256_kernel<0,1,1><<<dim3(4,4,8), blk, 0, stream>>>(Wr, ctx, nullptr, att, wdw, Mbb);

    // out = Mbb @ qT^T + wdw0*br
    mfma_nt<3,1><<<dim3(32,2,8), blk, 0, stream>>>(Mbb, 65536, 256, qTb, CHW, 256,
                                                   out, CHW, 4096, 256, br, wdw);
}

// Round 5
// 198.523 us; speedup vs baseline: 4.8302x; 1.0819x over previous
//
#include <hip/hip_runtime.h>
#include <math.h>

#define BB_ 8
#define CC_ 256
#define HWSZ 4096            // 64*64
#define CHW (CC_*HWSZ)       // 1,048,576
#define BCHW (BB_*CHW)       // 8,388,608

typedef __attribute__((ext_vector_type(8))) short short8v;
typedef __attribute__((ext_vector_type(4))) float f32x4;

struct Taps5 { float t[5]; };

__device__ inline ushort f2b(float f){
    uint u = __float_as_uint(f);
    u += 0x7FFF + ((u >> 16) & 1);
    return (ushort)(u >> 16);
}
__device__ inline float b2f(ushort u){
    return __uint_as_float(((uint)u) << 16);
}
__device__ inline ushort f2h(float f){
    _Float16 h = (_Float16)f; ushort u; __builtin_memcpy(&u, &h, 2); return u;
}
__device__ inline float h2f(ushort u){
    _Float16 h; __builtin_memcpy(&h, &u, 2); return (float)h;
}
// async 16B global -> LDS (linear dest = wave-uniform base + lane*16)
__device__ __forceinline__ void gload16(const ushort* g, ushort* l){
    __builtin_amdgcn_global_load_lds(
        (const __attribute__((address_space(1))) void*)g,
        (__attribute__((address_space(3))) void*)l, 16, 0, 0);
}

// ---------------- prep: x f32 -> xb bf16 (natural) + xTb bf16 ([hw][c]) ----------------
__global__ __launch_bounds__(256) void prepx_kernel(const float* __restrict__ x,
        ushort* __restrict__ xb, ushort* __restrict__ xTb){
    const int b = blockIdx.z, c0 = blockIdx.y*64, h0 = blockIdx.x*64;
    const float* xp = x + (size_t)b*CHW;
    __shared__ float T[64][65];
    const int tid = threadIdx.x;
    const int cl = tid >> 4;            // 0..15
    const int hl = (tid & 15) * 4;      // 0..60
    #pragma unroll
    for (int p = 0; p < 4; ++p){
        int c = c0 + p*16 + cl;
        float4 v = *(const float4*)&xp[(size_t)c*4096 + h0 + hl];
        ushort4 u; u.x = f2b(v.x); u.y = f2b(v.y); u.z = f2b(v.z); u.w = f2b(v.w);
        *(ushort4*)&xb[(size_t)b*CHW + (size_t)c*4096 + h0 + hl] = u;
        T[p*16+cl][hl+0] = v.x;
        T[p*16+cl][hl+1] = v.y;
        T[p*16+cl][hl+2] = v.z;
        T[p*16+cl][hl+3] = v.w;
    }
    __syncthreads();
    const int hr = tid >> 2;            // 0..63
    const int cs = (tid & 3) * 16;      // 0..48
    short8v o0, o1;
    #pragma unroll
    for (int i = 0; i < 8; ++i) o0[i] = (short)f2b(T[cs+i][hr]);
    #pragma unroll
    for (int i = 0; i < 8; ++i) o1[i] = (short)f2b(T[cs+8+i][hr]);
    ushort* dst = xTb + (size_t)b*CHW + (size_t)(h0+hr)*256 + c0 + cs;
    *(short8v*)dst = o0;
    *(short8v*)(dst+8) = o1;
}

// ---------------- fused pyramid + 3 plane softmaxes, per (b,c) plane ----------------
__global__ __launch_bounds__(256) void plane5_kernel(const float* __restrict__ x,
        ushort* __restrict__ P, ushort* __restrict__ S1, ushort* __restrict__ S2,
        Taps5 t3, Taps5 t5){
    const size_t base = (size_t)blockIdx.x * HWSZ;
    const int tid = threadIdx.x;
    const int r  = tid >> 2;           // 0..63
    const int cq = (tid & 3) * 16;     // 0,16,32,48
    __shared__ float X[64*65];
    __shared__ float T[64*65];
    __shared__ float G[64*65];
    #pragma unroll
    for (int i = 0; i < 4; ++i){
        float4 v = *reinterpret_cast<const float4*>(&x[base + r*64 + cq + i*4]);
        X[r*65 + cq + i*4 + 0] = v.x;
        X[r*65 + cq + i*4 + 1] = v.y;
        X[r*65 + cq + i*4 + 2] = v.z;
        X[r*65 + cq + i*4 + 3] = v.w;
    }
    __syncthreads();
    #pragma unroll
    for (int j = 0; j < 16; ++j){
        int c = cq + j;
        float l = (c > 0)  ? X[r*65 + c - 1] : 0.f;
        float m = X[r*65 + c];
        float rr = (c < 63) ? X[r*65 + c + 1] : 0.f;
        T[r*65 + c] = t3.t[0]*l + t3.t[1]*m + t3.t[2]*rr;
    }
    __syncthreads();
    #pragma unroll
    for (int j = 0; j < 16; ++j){
        int c = cq + j;
        float u = (r > 0)  ? T[(r-1)*65 + c] : 0.f;
        float m = T[r*65 + c];
        float d = (r < 63) ? T[(r+1)*65 + c] : 0.f;
        G[r*65 + c] = t3.t[0]*u + t3.t[1]*m + t3.t[2]*d;
    }
    __syncthreads();
    #pragma unroll
    for (int j = 0; j < 16; ++j){
        int c = cq + j;
        float acc = 0.f;
        #pragma unroll
        for (int d = -2; d <= 2; ++d){
            int cc = c + d;
            float v = (cc >= 0 && cc < 64) ? G[r*65 + cc] : 0.f;
            acc += t5.t[d+2]*v;
        }
        T[r*65 + c] = acc;
    }
    __syncthreads();
    float vv[3][16];
    #pragma unroll
    for (int j = 0; j < 16; ++j){
        int c = cq + j;
        float g2 = 0.f;
        #pragma unroll
        for (int d = -2; d <= 2; ++d){
            int rr2 = r + d;
            float v = (rr2 >= 0 && rr2 < 64) ? T[rr2*65 + c] : 0.f;
            g2 += t5.t[d+2]*v;
        }
        float xv = X[r*65 + c];
        float g1 = G[r*65 + c];
        vv[0][j] = xv;
        vv[1][j] = xv - g1;
        vv[2][j] = g1 - g2;
    }
    const size_t o = base + r*64 + cq;
    {
        short8v a0, a1, b0, b1;
        #pragma unroll
        for (int i = 0; i < 8; ++i){
            a0[i] = (short)f2b(vv[1][i]);   a1[i] = (short)f2b(vv[1][8+i]);
            b0[i] = (short)f2b(vv[2][i]);   b1[i] = (short)f2b(vv[2][8+i]);
        }
        *(short8v*)&S1[o] = a0; *(short8v*)&S1[o+8] = a1;
        *(short8v*)&S2[o] = b0; *(short8v*)&S2[o+8] = b1;
    }
    __shared__ float redm[3][4], reds[3][4];
    const int wid = tid >> 6, lane = tid & 63;
    #pragma unroll
    for (int g = 0; g < 3; ++g){
        float mx = vv[g][0];
        #pragma unroll
        for (int j = 1; j < 16; ++j) mx = fmaxf(mx, vv[g][j]);
        #pragma unroll
        for (int off = 32; off > 0; off >>= 1) mx = fmaxf(mx, __shfl_xor(mx, off));
        if (lane == 0) redm[g][wid] = mx;
        __syncthreads();
        mx = fmaxf(fmaxf(redm[g][0], redm[g][1]), fmaxf(redm[g][2], redm[g][3]));
        float s = 0.f;
        #pragma unroll
        for (int j = 0; j < 16; ++j){ vv[g][j] = expf(vv[g][j] - mx); s += vv[g][j]; }
        #pragma unroll
        for (int off = 32; off > 0; off >>= 1) s += __shfl_xor(s, off);
        if (lane == 0) reds[g][wid] = s;
        __syncthreads();
        s = reds[g][0] + reds[g][1] + reds[g][2] + reds[g][3];
        float inv = 1.f / s;
        short8v p0, p1;
        #pragma unroll
        for (int i = 0; i < 8; ++i){
            p0[i] = (short)f2b(vv[g][i]*inv);
            p1[i] = (short)f2b(vv[g][8+i]*inv);
        }
        ushort* Pg = P + (size_t)g*BCHW;
        *(short8v*)&Pg[o] = p0; *(short8v*)&Pg[o+8] = p1;
    }
}

// ---------------- row softmax over HW (4096), f16 in, bf16 out ----------------
__global__ __launch_bounds__(256) void rowsm_kernel(const ushort* __restrict__ inp,
                                                    ushort* __restrict__ outp){
    const size_t base = (size_t)blockIdx.x * HWSZ + threadIdx.x * 16;
    const int tid = threadIdx.x;
    float v[16];
    {
        short8v a = *(const short8v*)(inp + base);
        short8v b = *(const short8v*)(inp + base + 8);
        #pragma unroll
        for (int i = 0; i < 8; ++i){ v[i] = h2f((ushort)a[i]); v[8+i] = h2f((ushort)b[i]); }
    }
    float m = v[0];
    #pragma unroll
    for (int i = 1; i < 16; ++i) m = fmaxf(m, v[i]);
    #pragma unroll
    for (int off = 32; off > 0; off >>= 1) m = fmaxf(m, __shfl_xor(m, off));
    __shared__ float redm[4], reds[4];
    int wid = tid >> 6, lane = tid & 63;
    if (lane == 0) redm[wid] = m;
    __syncthreads();
    m = fmaxf(fmaxf(redm[0], redm[1]), fmaxf(redm[2], redm[3]));
    float s = 0.f;
    #pragma unroll
    for (int i = 0; i < 16; ++i){ v[i] = expf(v[i] - m); s += v[i]; }
    #pragma unroll
    for (int off = 32; off > 0; off >>= 1) s += __shfl_xor(s, off);
    if (lane == 0) reds[wid] = s;
    __syncthreads();
    s = reds[0] + reds[1] + reds[2] + reds[3];
    float inv = 1.f / s;
    short8v o0, o1;
    #pragma unroll
    for (int i = 0; i < 8; ++i){ o0[i] = (short)f2b(v[i]*inv); o1[i] = (short)f2b(v[8+i]*inv); }
    ushort* op = outp + base;
    *(short8v*)op = o0; *(short8v*)(op+8) = o1;
}

// ---------------- MFMA NT GEMM: C[m,n] = sum_k A[m,k]*B[n,k] (+epi) ----------------
// 128x128 tile, 4 waves of 64x64, bf16 operands. global_load_lds staging with
// pre-swizzled source (swizzle reduces to lane-only: (l&7)^(l>>3)).
// z = bb*KC + kc; EPI: 0 none, 1 +bias[m], 3 +wdw[2m]*bias[m]
// POUT: 0 f32 out, 1 f16 out
template<int EPI, int KC, int POUT>
__global__ __launch_bounds__(256) void mfma_nt(
        const ushort* __restrict__ A, size_t Abstride, int lda,
        const ushort* __restrict__ B, size_t Bbstride, int ldb,
        void* __restrict__ C, size_t Czstride, int ldc,
        int Kchunk, const float* __restrict__ bias, const float* __restrict__ wdw){
    __shared__ ushort As[128*64];
    __shared__ ushort Bs[128*64];
    const int z = blockIdx.z;
    const int bb = z / KC;
    const int kc = z % KC;
    const int m0 = blockIdx.y * 128, n0 = blockIdx.x * 128;
    const int kbeg = kc * Kchunk;
    const int tid = threadIdx.x;
    const int l = tid & 63, w = tid >> 6;
    const int wm = (w >> 1) * 64, wn = (w & 1) * 64;
    // staging addresses: wave w, instr i covers rows w*32+i*8+(l>>3), k-grp (l&7)
    const int lr8 = l >> 3;                       // 0..7 == row&7
    const int lk = ((l & 7) ^ lr8) << 3;          // pre-swizzled k element offset
    const ushort* Ag = A + (size_t)bb*Abstride + (size_t)(m0 + w*32 + lr8)*lda + kbeg + lk;
    const ushort* Bg = B + (size_t)bb*Bbstride + (size_t)(n0 + w*32 + lr8)*ldb + kbeg + lk;
    int rabase[4], raswz[4], rbbase[4], rbswz[4];
    #pragma unroll
    for (int f = 0; f < 4; ++f){
        int ra = wm + f*16 + (l & 15);
        int rb = wn + f*16 + (l & 15);
        rabase[f] = ra*64 + (l>>4)*8;  raswz[f] = (ra & 7) << 3;
        rbbase[f] = rb*64 + (l>>4)*8;  rbswz[f] = (rb & 7) << 3;
    }
    f32x4 acc[4][4] = {};
    const int ktiles = Kchunk >> 6;
    for (int kt = 0; kt < ktiles; ++kt){
        #pragma unroll
        for (int i = 0; i < 4; ++i){
            gload16(Ag + (size_t)i*8*lda + kt*64, &As[(w*32 + i*8)*64]);
            gload16(Bg + (size_t)i*8*ldb + kt*64, &Bs[(w*32 + i*8)*64]);
        }
        __syncthreads();
        #pragma unroll
        for (int ks = 0; ks < 2; ++ks){
            short8v af[4], bf[4];
            #pragma unroll
            for (int f = 0; f < 4; ++f){
                af[f] = *(const short8v*)&As[(rabase[f] + ks*32) ^ raswz[f]];
                bf[f] = *(const short8v*)&Bs[(rbbase[f] + ks*32) ^ rbswz[f]];
            }
            #pragma unroll
            for (int fi = 0; fi < 4; ++fi)
                #pragma unroll
                for (int fj = 0; fj < 4; ++fj)
                    acc[fi][fj] = __builtin_amdgcn_mfma_f32_16x16x32_bf16(af[fi], bf[fj], acc[fi][fj], 0, 0, 0);
        }
        __syncthreads();
    }
    const int erow = (l >> 4) * 4, ecol = l & 15;
    #pragma unroll
    for (int fi = 0; fi < 4; ++fi){
        #pragma unroll
        for (int r = 0; r < 4; ++r){
            const int m = m0 + wm + fi*16 + erow + r;
            float madd = 0.f;
            if (EPI == 1) madd = bias[m];
            else if (EPI == 3) madd = wdw[2*m]*bias[m];
            #pragma unroll
            for (int fj = 0; fj < 4; ++fj){
                const int n = n0 + wn + fj*16 + ecol;
                float v = acc[fi][fj][r];
                if (EPI == 1 || EPI == 3) v += madd;
                size_t idx = (size_t)z*Czstride + (size_t)m*ldc + n;
                if (POUT == 0) ((float*)C)[idx] = v;
                else           ((ushort*)C)[idx] = f2h(v);
            }
        }
    }
}

// ---------------- fused: 3x (reduce 8 f16 partials + softmax(256)) + sum -> att ----------------
__global__ __launch_bounds__(256) void rsa3_kernel(const ushort* __restrict__ part,
                                                   float* __restrict__ att){
    const int row = blockIdx.x;      // b*256 + c
    const int b = row >> 8;
    const int tid = threadIdx.x;
    const int wid = tid >> 6, lane = tid & 63;
    __shared__ float redm[3][4], reds[3][4];
    float r[3];
    #pragma unroll
    for (int g = 0; g < 3; ++g){
        const size_t base = (((size_t)((g*8 + b)*8)) << 16) + (size_t)(row & 255)*256 + tid;
        float v = 0.f;
        #pragma unroll
        for (int kc = 0; kc < 8; ++kc) v += h2f(part[base + ((size_t)kc << 16)]);
        float m = v;
        #pragma unroll
        for (int off = 32; off > 0; off >>= 1) m = fmaxf(m, __shfl_xor(m, off));
        if (lane == 0) redm[g][wid] = m;
        __syncthreads();
        m = fmaxf(fmaxf(redm[g][0], redm[g][1]), fmaxf(redm[g][2], redm[g][3]));
        float e = expf(v - m);
        float s = e;
        #pragma unroll
        for (int off = 32; off > 0; off >>= 1) s += __shfl_xor(s, off);
        if (lane == 0) reds[g][wid] = s;
        __syncthreads();
        s = reds[g][0] + reds[g][1] + reds[g][2] + reds[g][3];
        r[g] = e / s;
    }
    att[(size_t)row*256 + tid] = r[0] + r[1] + r[2];
}

// ---------------- reduce 8 split-K f32 partials (KX) ----------------
__global__ void reduce8_kernel(const float* __restrict__ part, float* __restrict__ G){
    int i = blockIdx.x*256 + threadIdx.x;    // over B*65536
    if (i >= BB_*65536) return;
    int b = i >> 16; int r = i & 65535;
    float s = 0.f;
    #pragma unroll
    for (int kc = 0; kc < 8; ++kc) s += part[(((size_t)(b*8 + kc)) << 16) + r];
    G[i] = s;
}

// ---------------- queries GEMM + fused softmax over C: qT[b,hw,c] bf16 ----------------
__global__ __launch_bounds__(256) void qgemm_sm(const ushort* __restrict__ xTb,
        const ushort* __restrict__ Wqb, const float* __restrict__ bq,
        ushort* __restrict__ qTb){
    __shared__ ushort As[128*64];
    __shared__ ushort Bs[256*64];
    const int b = blockIdx.z, m0 = blockIdx.x*128;
    const int tid = threadIdx.x, l = tid & 63, w = tid >> 6;
    const int wm = w*32;
    const int lr8 = l >> 3;
    const int lk = ((l & 7) ^ lr8) << 3;
    const ushort* Ag = xTb + (size_t)b*CHW + (size_t)(m0 + w*32 + lr8)*256 + lk;
    const ushort* Bg = Wqb + (size_t)(w*64 + lr8)*256 + lk;
    f32x4 acc[2][16] = {};
    for (int kt = 0; kt < 4; ++kt){
        #pragma unroll
        for (int i = 0; i < 4; ++i)
            gload16(Ag + (size_t)i*8*256 + kt*64, &As[(w*32 + i*8)*64]);
        #pragma unroll
        for (int i = 0; i < 8; ++i)
            gload16(Bg + (size_t)i*8*256 + kt*64, &Bs[(w*64 + i*8)*64]);
        __syncthreads();
        #pragma unroll
        for (int ks = 0; ks < 2; ++ks){
            short8v af[2];
            #pragma unroll
            for (int fi = 0; fi < 2; ++fi){
                int ar = wm + fi*16 + (l & 15);
                af[fi] = *(const short8v*)&As[(ar*64 + ks*32 + (l>>4)*8) ^ ((ar & 7) << 3)];
            }
            #pragma unroll
            for (int fj = 0; fj < 16; ++fj){
                int br = fj*16 + (l & 15);
                short8v bf = *(const short8v*)&Bs[(br*64 + ks*32 + (l>>4)*8) ^ ((br & 7) << 3)];
                acc[0][fj] = __builtin_amdgcn_mfma_f32_16x16x32_bf16(af[0], bf, acc[0][fj], 0, 0, 0);
                acc[1][fj] = __builtin_amdgcn_mfma_f32_16x16x32_bf16(af[1], bf, acc[1][fj], 0, 0, 0);
            }
        }
        __syncthreads();
    }
    const int ecol = l & 15, egrp = l >> 4;
    float bqv[16];
    #pragma unroll
    for (int fj = 0; fj < 16; ++fj) bqv[fj] = bq[fj*16 + ecol];
    #pragma unroll
    for (int fi = 0; fi < 2; ++fi){
        #pragma unroll
        for (int r = 0; r < 4; ++r){
            const int m = m0 + wm + fi*16 + egrp*4 + r;
            float v[16];
            float mx = -INFINITY;
            #pragma unroll
            for (int fj = 0; fj < 16; ++fj){
                v[fj] = acc[fi][fj][r] + bqv[fj];
                mx = fmaxf(mx, v[fj]);
            }
            #pragma unroll
            for (int off = 1; off < 16; off <<= 1) mx = fmaxf(mx, __shfl_xor(mx, off));
            float s = 0.f;
            #pragma unroll
            for (int fj = 0; fj < 16; ++fj){ v[fj] = expf(v[fj] - mx); s += v[fj]; }
            #pragma unroll
            for (int off = 1; off < 16; off <<= 1) s += __shfl_xor(s, off);
            float inv = 1.f / s;
            ushort* op = qTb + (size_t)b*CHW + (size_t)m*256 + ecol;
            #pragma unroll
            for (int fj = 0; fj < 16; ++fj) op[fj*16] = f2b(v[fj]*inv);
        }
    }
}

// ---------------- small NT gemm 256x256x256 per-batch (f32 VALU) ----------------
// EPI 0: f32 out, + bias[n] ; EPI 1: bf16 out, wdw[2m]*acc + wdw[2m+1]*att[b,n,m]
template<int ABATCH, int BBATCH, int EPI>
__global__ __launch_bounds__(256) void nt256_kernel(const float* __restrict__ A,
        const float* __restrict__ B, const float* __restrict__ bias,
        const float* __restrict__ att, const float* __restrict__ wdw,
        void* __restrict__ Cout){
    const int bb = blockIdx.z;
    const int m0 = blockIdx.y * 64, n0 = blockIdx.x * 64;
    const float* Ab = ABATCH ? A + (size_t)bb*65536 : A;
    const float* Bb = BBATCH ? B + (size_t)bb*65536 : B;
    __shared__ float Au[32*68];
    __shared__ float Bu[32*68];
    const int tid = threadIdx.x;
    const int tx = tid & 15, ty = tid >> 4;
    const int row = tid >> 2, loff = (tid & 3) * 8;
    float acc[4][4] = {};
    for (int k0 = 0; k0 < 256; k0 += 32){
        float4 a0 = *(const float4*)&Ab[(size_t)(m0+row)*256 + k0 + loff];
        float4 a1 = *(const float4*)&Ab[(size_t)(m0+row)*256 + k0 + loff + 4];
        float4 b0 = *(const float4*)&Bb[(size_t)(n0+row)*256 + k0 + loff];
        float4 b1 = *(const float4*)&Bb[(size_t)(n0+row)*256 + k0 + loff + 4];
        Au[(loff+0)*68 + row] = a0.x;
        Au[(loff+1)*68 + row] = a0.y;
        Au[(loff+2)*68 + row] = a0.z;
        Au[(loff+3)*68 + row] = a0.w;
        Au[(loff+4)*68 + row] = a1.x;
        Au[(loff+5)*68 + row] = a1.y;
        Au[(loff+6)*68 + row] = a1.z;
        Au[(loff+7)*68 + row] = a1.w;
        Bu[(loff+0)*68 + row] = b0.x;
        Bu[(loff+1)*68 + row] = b0.y;
        Bu[(loff+2)*68 + row] = b0.z;
        Bu[(loff+3)*68 + row] = b0.w;
        Bu[(loff+4)*68 + row] = b1.x;
        Bu[(loff+5)*68 + row] = b1.y;
        Bu[(loff+6)*68 + row] = b1.z;
        Bu[(loff+7)*68 + row] = b1.w;
        __syncthreads();
        #pragma unroll
        for (int kk = 0; kk < 32; ++kk){
            float4 av = *(const float4*)&Au[kk*68 + ty*4];
            float4 bv = *(const float4*)&Bu[kk*68 + tx*4];
            float aa[4] = {av.x, av.y, av.z, av.w};
            float bb2[4] = {bv.x, bv.y, bv.z, bv.w};
            #pragma unroll
            for (int i = 0; i < 4; ++i)
                #pragma unroll
                for (int j = 0; j < 4; ++j)
                    acc[i][j] += aa[i]*bb2[j];
        }
        __syncthreads();
    }
    #pragma unroll
    for (int i = 0; i < 4; ++i){
        int m = m0 + ty*4 + i;
        if (EPI == 0){
            float4 wv;
            float* wp = &wv.x;
            #pragma unroll
            for (int j = 0; j < 4; ++j) wp[j] = acc[i][j] + bias[n0 + tx*4 + j];
            *(float4*)&((float*)Cout)[(size_t)bb*65536 + (size_t)m*256 + n0 + tx*4] = wv;
        } else {
            ushort4 uv;
            ushort* up = &uv.x;
            #pragma unroll
            for (int j = 0; j < 4; ++j){
                int n = n0 + tx*4 + j;
                float v = wdw[2*m]*acc[i][j] + wdw[2*m+1]*att[(size_t)bb*65536 + (size_t)n*256 + m];
                up[j] = f2b(v);
            }
            *(ushort4*)&((ushort*)Cout)[(size_t)bb*65536 + (size_t)m*256 + n0 + tx*4] = uv;
        }
    }
}

// ---------------- f32 -> bf16 convert for Wk and Wq (merged) ----------------
__global__ void cvtW_kernel(const float* __restrict__ Wk, const float* __restrict__ Wq,
                            ushort* __restrict__ Wkb, ushort* __restrict__ Wqb){
    int blk = blockIdx.x;
    const float* src = (blk < 64) ? Wk : Wq;
    ushort* dst = (blk < 64) ? Wkb : Wqb;
    int i = (blk & 63)*256 + threadIdx.x;
    float4 v = *(const float4*)&src[i*4];
    ushort4 u; u.x = f2b(v.x); u.y = f2b(v.y); u.z = f2b(v.z); u.w = f2b(v.w);
    *(ushort4*)&dst[i*4] = u;
}

// ---------------- host ----------------
extern "C" void kernel_launch(void* const* d_in, const int* in_sizes, int n_in,
                              void* d_out, int out_size, void* d_ws, size_t ws_size,
                              hipStream_t stream){
    const float* x   = (const float*)d_in[0];
    const float* Wk  = (const float*)d_in[1];
    const float* bk  = (const float*)d_in[2];
    const float* Wq  = (const float*)d_in[3];
    const float* bq  = (const float*)d_in[4];
    const float* Wv  = (const float*)d_in[5];
    const float* bv  = (const float*)d_in[6];
    const float* Wr  = (const float*)d_in[7];
    const float* br  = (const float*)d_in[8];
    const float* wdw = (const float*)d_in[9];
    float* out = (float*)d_out;

    char* w = (char*)d_ws;
    ushort* S    = (ushort*)w; w += (size_t)3*BCHW*2;        // S0=xb, S1=L1, S2=L2
    ushort* xTb  = (ushort*)w; w += (size_t)BCHW*2;
    ushort* P    = (ushort*)w; w += (size_t)3*BCHW*2;        // P0,P1,P2; later keysb/qTb
    char*   preg = w;          w += (size_t)3*8*8*65536*2;   // 25.2MB shared partial region
    float*  att  = (float*)w;  w += (size_t)BB_*65536*4;
    float*  KX   = (float*)w;  w += (size_t)BB_*65536*4;
    float*  ctx  = (float*)w;  w += (size_t)BB_*65536*4;
    ushort* Mbb  = (ushort*)w; w += (size_t)BB_*65536*2;
    ushort* Wkb  = (ushort*)w; w += 65536*2;
    ushort* Wqb  = (ushort*)w; w += 65536*2;
    ushort* partH = (ushort*)preg;   // gram3 partials f16 (3*8*8*65536)
    ushort* FreH  = (ushort*)preg;   // keys_pre f16 (BCHW), alias after rsa3
    float*  partK = (float*)preg;    // KX partials f32 (8*8*65536), alias after rowsm
    ushort* keysb = P;               // reuse P after gram3
    ushort* qTb   = P + (size_t)BCHW;

    Taps5 T3{}, T5{};
    {
        double g[5], s;
        s = 0; for (int i = 0; i < 3; ++i){ double d = i - 1.0; g[i] = exp(-d*d/(2.0*1.6*1.6)); s += g[i]; }
        for (int i = 0; i < 3; ++i) T3.t[i] = (float)(g[i]/s);
        double sig = 1.6 * pow(2.0, 1.0/3.0);
        s = 0; for (int i = 0; i < 5; ++i){ double d = i - 2.0; g[i] = exp(-d*d/(2.0*sig*sig)); s += g[i]; }
        for (int i = 0; i < 5; ++i) T5.t[i] = (float)(g[i]/s);
    }

    const dim3 blk(256);

    // prep + pyramid (+3 plane softmaxes) + weight converts
    prepx_kernel<<<dim3(64,4,8), blk, 0, stream>>>(x, S, xTb);
    plane5_kernel<<<BB_*CC_, blk, 0, stream>>>(x, P, S + (size_t)BCHW, S + (size_t)2*BCHW, T3, T5);
    cvtW_kernel<<<128, blk, 0, stream>>>(Wk, Wq, Wkb, Wqb);

    // 3 chan-att grams in one launch: z = (g*8+b)*8 + kc, K-chunk 512, f16 partials
    mfma_nt<0,8,1><<<dim3(2,2,192), blk, 0, stream>>>(P, CHW, 4096, S, CHW, 4096,
                                                      partH, 65536, 256, 512, nullptr, nullptr);
    rsa3_kernel<<<BB_*CC_, blk, 0, stream>>>(partH, att);

    // keys = rowsoftmax(Wk@x + bk)  (logits in f16)
    mfma_nt<1,1,1><<<dim3(32,2,8), blk, 0, stream>>>(Wkb, 0, 256, xTb, CHW, 256,
                                                     FreH, CHW, 4096, 256, bk, nullptr);
    rowsm_kernel<<<BB_*CC_, blk, 0, stream>>>(FreH, keysb);
    // KX = keys @ x^T (split-K 8, f32 partials)
    mfma_nt<0,8,0><<<dim3(2,2,64), blk, 0, stream>>>(keysb, CHW, 4096, S, CHW, 4096,
                                                     partK, 65536, 256, 512, nullptr, nullptr);
    reduce8_kernel<<<(BB_*65536)/256, blk, 0, stream>>>(partK, KX);

    // queriesT = softmax over C fused into GEMM epilogue
    qgemm_sm<<<dim3(32,1,8), blk, 0, stream>>>(xTb, Wqb, bq, qTb);

    // ctx[b,k,v] = sum_c KX[b,k,c]*Wv[v,c] + bv[v]
    nt256_kernel<1,0,0><<<dim3(4,4,8), blk, 0, stream>>>(KX, Wv, bv, nullptr, nullptr, ctx);
    // Mbb[b,m,k] = bf16( wdw0[m]*(sum_v Wr[m,v]*ctx[b,k,v]) + wdw1[m]*att[b,k,m] )
    nt256_kernel<0,1,1><<<dim3(4,4,8), blk, 0, stream>>>(Wr, ctx, nullptr, att, wdw, Mbb);

    // out = Mbb @ qT^T + wdw0*br
    mfma_nt<3,1,0><<<dim3(32,2,8), blk, 0, stream>>>(Mbb, 65536, 256, qTb, CHW, 256,
                                                     out, CHW, 4096, 256, br, wdw);
}

// Round 6
// 192.891 us; speedup vs baseline: 4.9713x; 1.0292x over previous
//
#include <hip/hip_runtime.h>
#include <math.h>

#define BB_ 8
#define CC_ 256
#define HWSZ 4096            // 64*64
#define CHW (CC_*HWSZ)       // 1,048,576
#define BCHW (BB_*CHW)       // 8,388,608

typedef __attribute__((ext_vector_type(8))) short short8v;
typedef __attribute__((ext_vector_type(4))) float f32x4;

struct Taps5 { float t[5]; };

__device__ inline ushort f2b(float f){
    uint u = __float_as_uint(f);
    u += 0x7FFF + ((u >> 16) & 1);
    return (ushort)(u >> 16);
}
__device__ inline float b2f(ushort u){
    return __uint_as_float(((uint)u) << 16);
}
__device__ inline ushort f2h(float f){
    _Float16 h = (_Float16)f; ushort u; __builtin_memcpy(&u, &h, 2); return u;
}
__device__ inline float h2f(ushort u){
    _Float16 h; __builtin_memcpy(&h, &u, 2); return (float)h;
}
// async 16B global -> LDS (linear dest = wave-uniform base + lane*16)
__device__ __forceinline__ void gload16(const ushort* g, ushort* l){
    __builtin_amdgcn_global_load_lds(
        (const __attribute__((address_space(1))) void*)g,
        (__attribute__((address_space(3))) void*)l, 16, 0, 0);
}

// ---------------- prep: x f32 -> xb bf16 (natural) + xTb bf16 ([hw][c]) ----------------
__global__ __launch_bounds__(256) void prepx_kernel(const float* __restrict__ x,
        ushort* __restrict__ xb, ushort* __restrict__ xTb){
    const int b = blockIdx.z, c0 = blockIdx.y*64, h0 = blockIdx.x*64;
    const float* xp = x + (size_t)b*CHW;
    __shared__ float T[64][65];
    const int tid = threadIdx.x;
    const int cl = tid >> 4;            // 0..15
    const int hl = (tid & 15) * 4;      // 0..60
    #pragma unroll
    for (int p = 0; p < 4; ++p){
        int c = c0 + p*16 + cl;
        float4 v = *(const float4*)&xp[(size_t)c*4096 + h0 + hl];
        ushort4 u; u.x = f2b(v.x); u.y = f2b(v.y); u.z = f2b(v.z); u.w = f2b(v.w);
        *(ushort4*)&xb[(size_t)b*CHW + (size_t)c*4096 + h0 + hl] = u;
        T[p*16+cl][hl+0] = v.x;
        T[p*16+cl][hl+1] = v.y;
        T[p*16+cl][hl+2] = v.z;
        T[p*16+cl][hl+3] = v.w;
    }
    __syncthreads();
    const int hr = tid >> 2;            // 0..63
    const int cs = (tid & 3) * 16;      // 0..48
    short8v o0, o1;
    #pragma unroll
    for (int i = 0; i < 8; ++i) o0[i] = (short)f2b(T[cs+i][hr]);
    #pragma unroll
    for (int i = 0; i < 8; ++i) o1[i] = (short)f2b(T[cs+8+i][hr]);
    ushort* dst = xTb + (size_t)b*CHW + (size_t)(h0+hr)*256 + c0 + cs;
    *(short8v*)dst = o0;
    *(short8v*)(dst+8) = o1;
}

// ---------------- fused pyramid + 3 plane softmaxes (shuffle-based) ----------------
// thread: column c = tid&63, row-block rb = tid>>6 (rows rb*16..rb*16+15)
__global__ __launch_bounds__(256) void plane6_kernel(const float* __restrict__ x,
        ushort* __restrict__ P, ushort* __restrict__ S1, ushort* __restrict__ S2,
        Taps5 t3, Taps5 t5){
    const size_t base = (size_t)blockIdx.x * HWSZ;
    const int tid = threadIdx.x;
    const int c = tid & 63, rb = tid >> 6;
    float v[16];
    #pragma unroll
    for (int i = 0; i < 16; ++i) v[i] = x[base + (rb*16 + i)*64 + c];
    // horizontal 3-tap (zero pad) via shuffles
    float h3[16];
    #pragma unroll
    for (int i = 0; i < 16; ++i){
        float l = __shfl(v[i], c-1, 64); l = (c > 0)  ? l : 0.f;
        float r = __shfl(v[i], c+1, 64); r = (c < 63) ? r : 0.f;
        h3[i] = t3.t[0]*l + t3.t[1]*v[i] + t3.t[2]*r;
    }
    // vertical 3-tap: boundary rows via LDS
    __shared__ float bndA[4][2][64];
    bndA[rb][0][c] = h3[0]; bndA[rb][1][c] = h3[15];
    __syncthreads();
    const float upA = (rb > 0) ? bndA[rb-1][1][c] : 0.f;
    const float dnA = (rb < 3) ? bndA[rb+1][0][c] : 0.f;
    float g1[16];
    #pragma unroll
    for (int i = 0; i < 16; ++i){
        float a = (i > 0)  ? h3[i-1] : upA;
        float b = (i < 15) ? h3[i+1] : dnA;
        g1[i] = t3.t[0]*a + t3.t[1]*h3[i] + t3.t[2]*b;
    }
    // horizontal 5-tap on g1 (reuse h3 as h5)
    #pragma unroll
    for (int i = 0; i < 16; ++i){
        float m2 = __shfl(g1[i], c-2, 64); m2 = (c > 1)  ? m2 : 0.f;
        float m1 = __shfl(g1[i], c-1, 64); m1 = (c > 0)  ? m1 : 0.f;
        float p1 = __shfl(g1[i], c+1, 64); p1 = (c < 63) ? p1 : 0.f;
        float p2 = __shfl(g1[i], c+2, 64); p2 = (c < 62) ? p2 : 0.f;
        h3[i] = t5.t[0]*m2 + t5.t[1]*m1 + t5.t[2]*g1[i] + t5.t[3]*p1 + t5.t[4]*p2;
    }
    // vertical 5-tap: 2 boundary rows each side via LDS
    __shared__ float bndB[4][4][64];
    bndB[rb][0][c] = h3[0];  bndB[rb][1][c] = h3[1];
    bndB[rb][2][c] = h3[14]; bndB[rb][3][c] = h3[15];
    __syncthreads();
    const float u2 = (rb > 0) ? bndB[rb-1][2][c] : 0.f;   // global row rb*16-2
    const float u1 = (rb > 0) ? bndB[rb-1][3][c] : 0.f;   // global row rb*16-1
    const float d1 = (rb < 3) ? bndB[rb+1][0][c] : 0.f;   // global row rb*16+16
    const float d2 = (rb < 3) ? bndB[rb+1][1][c] : 0.f;   // global row rb*16+17
    float g2[16];
    #pragma unroll
    for (int i = 0; i < 16; ++i){
        float a = (i >= 2) ? h3[i-2] : (i == 1 ? u1 : u2);
        float b = (i >= 1) ? h3[i-1] : u1;
        float d = (i < 15) ? h3[i+1] : d1;
        float e = (i < 14) ? h3[i+2] : (i == 14 ? d1 : d2);
        g2[i] = t5.t[0]*a + t5.t[1]*b + t5.t[2]*h3[i] + t5.t[3]*d + t5.t[4]*e;
    }
    const size_t orow = base + (size_t)rb*16*64 + c;
    // raw L1, L2 (bf16)
    #pragma unroll
    for (int i = 0; i < 16; ++i){
        S1[orow + i*64] = f2b(v[i] - g1[i]);
        S2[orow + i*64] = f2b(g1[i] - g2[i]);
    }
    // 3 plane softmaxes
    __shared__ float redm[3][4], reds[3][4];
    const int wid = tid >> 6, lane = tid & 63;
    #pragma unroll
    for (int g = 0; g < 3; ++g){
        float val[16];
        #pragma unroll
        for (int i = 0; i < 16; ++i)
            val[i] = (g == 0) ? v[i] : (g == 1 ? v[i] - g1[i] : g1[i] - g2[i]);
        float mx = val[0];
        #pragma unroll
        for (int i = 1; i < 16; ++i) mx = fmaxf(mx, val[i]);
        #pragma unroll
        for (int off = 32; off > 0; off >>= 1) mx = fmaxf(mx, __shfl_xor(mx, off));
        if (lane == 0) redm[g][wid] = mx;
        __syncthreads();
        mx = fmaxf(fmaxf(redm[g][0], redm[g][1]), fmaxf(redm[g][2], redm[g][3]));
        float s = 0.f;
        #pragma unroll
        for (int i = 0; i < 16; ++i){ val[i] = expf(val[i] - mx); s += val[i]; }
        #pragma unroll
        for (int off = 32; off > 0; off >>= 1) s += __shfl_xor(s, off);
        if (lane == 0) reds[g][wid] = s;
        __syncthreads();
        s = reds[g][0] + reds[g][1] + reds[g][2] + reds[g][3];
        float inv = 1.f / s;
        ushort* Pg = P + (size_t)g*BCHW;
        #pragma unroll
        for (int i = 0; i < 16; ++i) Pg[orow + i*64] = f2b(val[i]*inv);
    }
}

// ---------------- row softmax over HW (4096), f16 in, bf16 out ----------------
__global__ __launch_bounds__(256) void rowsm_kernel(const ushort* __restrict__ inp,
                                                    ushort* __restrict__ outp){
    const size_t base = (size_t)blockIdx.x * HWSZ + threadIdx.x * 16;
    const int tid = threadIdx.x;
    float v[16];
    {
        short8v a = *(const short8v*)(inp + base);
        short8v b = *(const short8v*)(inp + base + 8);
        #pragma unroll
        for (int i = 0; i < 8; ++i){ v[i] = h2f((ushort)a[i]); v[8+i] = h2f((ushort)b[i]); }
    }
    float m = v[0];
    #pragma unroll
    for (int i = 1; i < 16; ++i) m = fmaxf(m, v[i]);
    #pragma unroll
    for (int off = 32; off > 0; off >>= 1) m = fmaxf(m, __shfl_xor(m, off));
    __shared__ float redm[4], reds[4];
    int wid = tid >> 6, lane = tid & 63;
    if (lane == 0) redm[wid] = m;
    __syncthreads();
    m = fmaxf(fmaxf(redm[0], redm[1]), fmaxf(redm[2], redm[3]));
    float s = 0.f;
    #pragma unroll
    for (int i = 0; i < 16; ++i){ v[i] = expf(v[i] - m); s += v[i]; }
    #pragma unroll
    for (int off = 32; off > 0; off >>= 1) s += __shfl_xor(s, off);
    if (lane == 0) reds[wid] = s;
    __syncthreads();
    s = reds[0] + reds[1] + reds[2] + reds[3];
    float inv = 1.f / s;
    short8v o0, o1;
    #pragma unroll
    for (int i = 0; i < 8; ++i){ o0[i] = (short)f2b(v[i]*inv); o1[i] = (short)f2b(v[8+i]*inv); }
    ushort* op = outp + base;
    *(short8v*)op = o0; *(short8v*)(op+8) = o1;
}

// ---------------- MFMA NT GEMM: C[m,n] = sum_k A[m,k]*B[n,k] (+epi) ----------------
// 128x128 tile, 4 waves of 64x64, bf16 operands. global_load_lds staging with
// pre-swizzled source. z = bb*KC + kc; EPI: 0 none, 1 +bias[m], 3 +wdw[2m]*bias[m]
// POUT: 0 f32 out, 1 f16 out
template<int EPI, int KC, int POUT>
__global__ __launch_bounds__(256) void mfma_nt(
        const ushort* __restrict__ A, size_t Abstride, int lda,
        const ushort* __restrict__ B, size_t Bbstride, int ldb,
        void* __restrict__ C, size_t Czstride, int ldc,
        int Kchunk, const float* __restrict__ bias, const float* __restrict__ wdw){
    __shared__ ushort As[128*64];
    __shared__ ushort Bs[128*64];
    const int z = blockIdx.z;
    const int bb = z / KC;
    const int kc = z % KC;
    const int m0 = blockIdx.y * 128, n0 = blockIdx.x * 128;
    const int kbeg = kc * Kchunk;
    const int tid = threadIdx.x;
    const int l = tid & 63, w = tid >> 6;
    const int wm = (w >> 1) * 64, wn = (w & 1) * 64;
    const int lr8 = l >> 3;
    const int lk = ((l & 7) ^ lr8) << 3;
    const ushort* Ag = A + (size_t)bb*Abstride + (size_t)(m0 + w*32 + lr8)*lda + kbeg + lk;
    const ushort* Bg = B + (size_t)bb*Bbstride + (size_t)(n0 + w*32 + lr8)*ldb + kbeg + lk;
    int rabase[4], raswz[4], rbbase[4], rbswz[4];
    #pragma unroll
    for (int f = 0; f < 4; ++f){
        int ra = wm + f*16 + (l & 15);
        int rb = wn + f*16 + (l & 15);
        rabase[f] = ra*64 + (l>>4)*8;  raswz[f] = (ra & 7) << 3;
        rbbase[f] = rb*64 + (l>>4)*8;  rbswz[f] = (rb & 7) << 3;
    }
    f32x4 acc[4][4] = {};
    const int ktiles = Kchunk >> 6;
    for (int kt = 0; kt < ktiles; ++kt){
        #pragma unroll
        for (int i = 0; i < 4; ++i){
            gload16(Ag + (size_t)i*8*lda + kt*64, &As[(w*32 + i*8)*64]);
            gload16(Bg + (size_t)i*8*ldb + kt*64, &Bs[(w*32 + i*8)*64]);
        }
        __syncthreads();
        #pragma unroll
        for (int ks = 0; ks < 2; ++ks){
            short8v af[4], bf[4];
            #pragma unroll
            for (int f = 0; f < 4; ++f){
                af[f] = *(const short8v*)&As[(rabase[f] + ks*32) ^ raswz[f]];
                bf[f] = *(const short8v*)&Bs[(rbbase[f] + ks*32) ^ rbswz[f]];
            }
            #pragma unroll
            for (int fi = 0; fi < 4; ++fi)
                #pragma unroll
                for (int fj = 0; fj < 4; ++fj)
                    acc[fi][fj] = __builtin_amdgcn_mfma_f32_16x16x32_bf16(af[fi], bf[fj], acc[fi][fj], 0, 0, 0);
        }
        __syncthreads();
    }
    const int erow = (l >> 4) * 4, ecol = l & 15;
    #pragma unroll
    for (int fi = 0; fi < 4; ++fi){
        #pragma unroll
        for (int r = 0; r < 4; ++r){
            const int m = m0 + wm + fi*16 + erow + r;
            float madd = 0.f;
            if (EPI == 1) madd = bias[m];
            else if (EPI == 3) madd = wdw[2*m]*bias[m];
            #pragma unroll
            for (int fj = 0; fj < 4; ++fj){
                const int n = n0 + wn + fj*16 + ecol;
                float v = acc[fi][fj][r];
                if (EPI == 1 || EPI == 3) v += madd;
                size_t idx = (size_t)z*Czstride + (size_t)m*ldc + n;
                if (POUT == 0) ((float*)C)[idx] = v;
                else           ((ushort*)C)[idx] = f2h(v);
            }
        }
    }
}

// ---------------- fused: 3x (reduce 8 f16 partials + softmax(256)) + sum -> att ----------------
__global__ __launch_bounds__(256) void rsa3_kernel(const ushort* __restrict__ part,
                                                   float* __restrict__ att){
    const int row = blockIdx.x;      // b*256 + c
    const int b = row >> 8;
    const int tid = threadIdx.x;
    const int wid = tid >> 6, lane = tid & 63;
    __shared__ float redm[3][4], reds[3][4];
    float r[3];
    #pragma unroll
    for (int g = 0; g < 3; ++g){
        const size_t base = (((size_t)((g*8 + b)*8)) << 16) + (size_t)(row & 255)*256 + tid;
        float v = 0.f;
        #pragma unroll
        for (int kc = 0; kc < 8; ++kc) v += h2f(part[base + ((size_t)kc << 16)]);
        float m = v;
        #pragma unroll
        for (int off = 32; off > 0; off >>= 1) m = fmaxf(m, __shfl_xor(m, off));
        if (lane == 0) redm[g][wid] = m;
        __syncthreads();
        m = fmaxf(fmaxf(redm[g][0], redm[g][1]), fmaxf(redm[g][2], redm[g][3]));
        float e = expf(v - m);
        float s = e;
        #pragma unroll
        for (int off = 32; off > 0; off >>= 1) s += __shfl_xor(s, off);
        if (lane == 0) reds[g][wid] = s;
        __syncthreads();
        s = reds[g][0] + reds[g][1] + reds[g][2] + reds[g][3];
        r[g] = e / s;
    }
    att[(size_t)row*256 + tid] = r[0] + r[1] + r[2];
}

// ---------------- reduce 8 split-K f32 partials (KX) ----------------
__global__ void reduce8_kernel(const float* __restrict__ part, float* __restrict__ G){
    int i = blockIdx.x*256 + threadIdx.x;    // over B*65536
    if (i >= BB_*65536) return;
    int b = i >> 16; int r = i & 65535;
    float s = 0.f;
    #pragma unroll
    for (int kc = 0; kc < 8; ++kc) s += part[(((size_t)(b*8 + kc)) << 16) + r];
    G[i] = s;
}

// ---------------- queries GEMM + fused softmax over C: qT[b,hw,c] bf16 ----------------
__global__ __launch_bounds__(256) void qgemm_sm(const ushort* __restrict__ xTb,
        const ushort* __restrict__ Wqb, const float* __restrict__ bq,
        ushort* __restrict__ qTb){
    __shared__ ushort As[128*64];
    __shared__ ushort Bs[256*64];
    const int b = blockIdx.z, m0 = blockIdx.x*128;
    const int tid = threadIdx.x, l = tid & 63, w = tid >> 6;
    const int wm = w*32;
    const int lr8 = l >> 3;
    const int lk = ((l & 7) ^ lr8) << 3;
    const ushort* Ag = xTb + (size_t)b*CHW + (size_t)(m0 + w*32 + lr8)*256 + lk;
    const ushort* Bg = Wqb + (size_t)(w*64 + lr8)*256 + lk;
    f32x4 acc[2][16] = {};
    for (int kt = 0; kt < 4; ++kt){
        #pragma unroll
        for (int i = 0; i < 4; ++i)
            gload16(Ag + (size_t)i*8*256 + kt*64, &As[(w*32 + i*8)*64]);
        #pragma unroll
        for (int i = 0; i < 8; ++i)
            gload16(Bg + (size_t)i*8*256 + kt*64, &Bs[(w*64 + i*8)*64]);
        __syncthreads();
        #pragma unroll
        for (int ks = 0; ks < 2; ++ks){
            short8v af[2];
            #pragma unroll
            for (int fi = 0; fi < 2; ++fi){
                int ar = wm + fi*16 + (l & 15);
                af[fi] = *(const short8v*)&As[(ar*64 + ks*32 + (l>>4)*8) ^ ((ar & 7) << 3)];
            }
            #pragma unroll
            for (int fj = 0; fj < 16; ++fj){
                int br = fj*16 + (l & 15);
                short8v bf = *(const short8v*)&Bs[(br*64 + ks*32 + (l>>4)*8) ^ ((br & 7) << 3)];
                acc[0][fj] = __builtin_amdgcn_mfma_f32_16x16x32_bf16(af[0], bf, acc[0][fj], 0, 0, 0);
                acc[1][fj] = __builtin_amdgcn_mfma_f32_16x16x32_bf16(af[1], bf, acc[1][fj], 0, 0, 0);
            }
        }
        __syncthreads();
    }
    const int ecol = l & 15, egrp = l >> 4;
    float bqv[16];
    #pragma unroll
    for (int fj = 0; fj < 16; ++fj) bqv[fj] = bq[fj*16 + ecol];
    #pragma unroll
    for (int fi = 0; fi < 2; ++fi){
        #pragma unroll
        for (int r = 0; r < 4; ++r){
            const int m = m0 + wm + fi*16 + egrp*4 + r;
            float v[16];
            float mx = -INFINITY;
            #pragma unroll
            for (int fj = 0; fj < 16; ++fj){
                v[fj] = acc[fi][fj][r] + bqv[fj];
                mx = fmaxf(mx, v[fj]);
            }
            #pragma unroll
            for (int off = 1; off < 16; off <<= 1) mx = fmaxf(mx, __shfl_xor(mx, off));
            float s = 0.f;
            #pragma unroll
            for (int fj = 0; fj < 16; ++fj){ v[fj] = expf(v[fj] - mx); s += v[fj]; }
            #pragma unroll
            for (int off = 1; off < 16; off <<= 1) s += __shfl_xor(s, off);
            float inv = 1.f / s;
            ushort* op = qTb + (size_t)b*CHW + (size_t)m*256 + ecol;
            #pragma unroll
            for (int fj = 0; fj < 16; ++fj) op[fj*16] = f2b(v[fj]*inv);
        }
    }
}

// ---------------- Wrv = Wr @ Wv  (NN, 256x256x256, f32 VALU) ----------------
__global__ __launch_bounds__(256) void wrw_kernel(const float* __restrict__ Wr,
        const float* __restrict__ Wv, float* __restrict__ Wrv){
    const int m0 = blockIdx.y * 64, n0 = blockIdx.x * 64;
    __shared__ float As[32][66];
    __shared__ float Bs[32][64];
    const int tid = threadIdx.x;
    const int tx = tid & 15, ty = tid >> 4;
    float acc[4][4] = {};
    for (int k0 = 0; k0 < 256; k0 += 32){
        int kk = tid & 31, ml = tid >> 5;
        #pragma unroll
        for (int r = 0; r < 8; ++r){
            int m = ml + r*8;
            As[kk][m] = Wr[(size_t)(m0+m)*256 + k0 + kk];
        }
        int j = tid & 63, kg = tid >> 6;
        #pragma unroll
        for (int r = 0; r < 8; ++r){
            int kk2 = kg + r*4;
            Bs[kk2][j] = Wv[(size_t)(k0+kk2)*256 + n0 + j];
        }
        __syncthreads();
        #pragma unroll
        for (int kk2 = 0; kk2 < 32; ++kk2){
            float4 bv4 = *(const float4*)&Bs[kk2][tx*4];
            float a0 = As[kk2][ty*4+0], a1 = As[kk2][ty*4+1];
            float a2 = As[kk2][ty*4+2], a3 = As[kk2][ty*4+3];
            float av[4] = {a0, a1, a2, a3};
            float bw[4] = {bv4.x, bv4.y, bv4.z, bv4.w};
            #pragma unroll
            for (int i = 0; i < 4; ++i)
                #pragma unroll
                for (int j2 = 0; j2 < 4; ++j2)
                    acc[i][j2] += av[i]*bw[j2];
        }
        __syncthreads();
    }
    #pragma unroll
    for (int i = 0; i < 4; ++i){
        float4 wv4 = {acc[i][0], acc[i][1], acc[i][2], acc[i][3]};
        *(float4*)&Wrv[(size_t)(m0+ty*4+i)*256 + n0 + tx*4] = wv4;
    }
}

// ---------------- small NT gemm 256x256x256 per-batch (f32 VALU) ----------------
// EPI 1: bf16 out, wdw[2m]*acc + wdw[2m+1]*att[b,n,m]
template<int ABATCH, int BBATCH, int EPI>
__global__ __launch_bounds__(256) void nt256_kernel(const float* __restrict__ A,
        const float* __restrict__ B, const float* __restrict__ bias,
        const float* __restrict__ att, const float* __restrict__ wdw,
        void* __restrict__ Cout){
    const int bb = blockIdx.z;
    const int m0 = blockIdx.y * 64, n0 = blockIdx.x * 64;
    const float* Ab = ABATCH ? A + (size_t)bb*65536 : A;
    const float* Bb = BBATCH ? B + (size_t)bb*65536 : B;
    __shared__ float Au[32*68];
    __shared__ float Bu[32*68];
    const int tid = threadIdx.x;
    const int tx = tid & 15, ty = tid >> 4;
    const int row = tid >> 2, loff = (tid & 3) * 8;
    float acc[4][4] = {};
    for (int k0 = 0; k0 < 256; k0 += 32){
        float4 a0 = *(const float4*)&Ab[(size_t)(m0+row)*256 + k0 + loff];
        float4 a1 = *(const float4*)&Ab[(size_t)(m0+row)*256 + k0 + loff + 4];
        float4 b0 = *(const float4*)&Bb[(size_t)(n0+row)*256 + k0 + loff];
        float4 b1 = *(const float4*)&Bb[(size_t)(n0+row)*256 + k0 + loff + 4];
        Au[(loff+0)*68 + row] = a0.x;
        Au[(loff+1)*68 + row] = a0.y;
        Au[(loff+2)*68 + row] = a0.z;
        Au[(loff+3)*68 + row] = a0.w;
        Au[(loff+4)*68 + row] = a1.x;
        Au[(loff+5)*68 + row] = a1.y;
        Au[(loff+6)*68 + row] = a1.z;
        Au[(loff+7)*68 + row] = a1.w;
        Bu[(loff+0)*68 + row] = b0.x;
        Bu[(loff+1)*68 + row] = b0.y;
        Bu[(loff+2)*68 + row] = b0.z;
        Bu[(loff+3)*68 + row] = b0.w;
        Bu[(loff+4)*68 + row] = b1.x;
        Bu[(loff+5)*68 + row] = b1.y;
        Bu[(loff+6)*68 + row] = b1.z;
        Bu[(loff+7)*68 + row] = b1.w;
        __syncthreads();
        #pragma unroll
        for (int kk = 0; kk < 32; ++kk){
            float4 av = *(const float4*)&Au[kk*68 + ty*4];
            float4 bv = *(const float4*)&Bu[kk*68 + tx*4];
            float aa[4] = {av.x, av.y, av.z, av.w};
            float bb2[4] = {bv.x, bv.y, bv.z, bv.w};
            #pragma unroll
            for (int i = 0; i < 4; ++i)
                #pragma unroll
                for (int j = 0; j < 4; ++j)
                    acc[i][j] += aa[i]*bb2[j];
        }
        __syncthreads();
    }
    #pragma unroll
    for (int i = 0; i < 4; ++i){
        int m = m0 + ty*4 + i;
        ushort4 uv;
        ushort* up = &uv.x;
        #pragma unroll
        for (int j = 0; j < 4; ++j){
            int n = n0 + tx*4 + j;
            float v = wdw[2*m]*acc[i][j] + wdw[2*m+1]*att[(size_t)bb*65536 + (size_t)n*256 + m];
            up[j] = f2b(v);
        }
        *(ushort4*)&((ushort*)Cout)[(size_t)bb*65536 + (size_t)m*256 + n0 + tx*4] = uv;
    }
}

// ---------------- weight converts + brc = br + Wr@bv ----------------
__global__ void cvtWB_kernel(const float* __restrict__ Wk, const float* __restrict__ Wq,
                             const float* __restrict__ Wr, const float* __restrict__ bv,
                             const float* __restrict__ br,
                             ushort* __restrict__ Wkb, ushort* __restrict__ Wqb,
                             float* __restrict__ brc){
    int blk = blockIdx.x;
    if (blk < 128){
        const float* src = (blk < 64) ? Wk : Wq;
        ushort* dst = (blk < 64) ? Wkb : Wqb;
        int i = (blk & 63)*256 + threadIdx.x;
        float4 v = *(const float4*)&src[i*4];
        ushort4 u; u.x = f2b(v.x); u.y = f2b(v.y); u.z = f2b(v.z); u.w = f2b(v.w);
        *(ushort4*)&dst[i*4] = u;
    } else {
        int m = (blk - 128)*16 + (threadIdx.x >> 4);
        int l16 = threadIdx.x & 15;
        float s = 0.f;
        #pragma unroll
        for (int t = 0; t < 4; ++t){
            float4 a = *(const float4*)&Wr[(size_t)m*256 + l16*16 + t*4];
            float4 b = *(const float4*)&bv[l16*16 + t*4];
            s += a.x*b.x + a.y*b.y + a.z*b.z + a.w*b.w;
        }
        #pragma unroll
        for (int off = 1; off < 16; off <<= 1) s += __shfl_xor(s, off);
        if (l16 == 0) brc[m] = br[m] + s;
    }
}

// ---------------- host ----------------
extern "C" void kernel_launch(void* const* d_in, const int* in_sizes, int n_in,
                              void* d_out, int out_size, void* d_ws, size_t ws_size,
                              hipStream_t stream){
    const float* x   = (const float*)d_in[0];
    const float* Wk  = (const float*)d_in[1];
    const float* bk  = (const float*)d_in[2];
    const float* Wq  = (const float*)d_in[3];
    const float* bq  = (const float*)d_in[4];
    const float* Wv  = (const float*)d_in[5];
    const float* bv  = (const float*)d_in[6];
    const float* Wr  = (const float*)d_in[7];
    const float* br  = (const float*)d_in[8];
    const float* wdw = (const float*)d_in[9];
    float* out = (float*)d_out;

    char* w = (char*)d_ws;
    ushort* S    = (ushort*)w; w += (size_t)3*BCHW*2;        // S0=xb, S1=L1, S2=L2
    ushort* xTb  = (ushort*)w; w += (size_t)BCHW*2;
    ushort* P    = (ushort*)w; w += (size_t)3*BCHW*2;        // P0,P1,P2; later keysb/qTb
    char*   preg = w;          w += (size_t)3*8*8*65536*2;   // 25.2MB shared partial region
    float*  att  = (float*)w;  w += (size_t)BB_*65536*4;
    float*  KX   = (float*)w;  w += (size_t)BB_*65536*4;
    ushort* Mbb  = (ushort*)w; w += (size_t)BB_*65536*2;
    ushort* Wkb  = (ushort*)w; w += 65536*2;
    ushort* Wqb  = (ushort*)w; w += 65536*2;
    float*  Wrv  = (float*)w;  w += 65536*4;
    float*  brc  = (float*)w;  w += 256*4;
    ushort* partH = (ushort*)preg;   // gram3 partials f16 (3*8*8*65536)
    ushort* FreH  = (ushort*)preg;   // keys_pre f16 (BCHW), alias after rsa3
    float*  partK = (float*)preg;    // KX partials f32 (8*8*65536), alias after rowsm
    ushort* keysb = P;               // reuse P after gram3
    ushort* qTb   = P + (size_t)BCHW;

    Taps5 T3{}, T5{};
    {
        double g[5], s;
        s = 0; for (int i = 0; i < 3; ++i){ double d = i - 1.0; g[i] = exp(-d*d/(2.0*1.6*1.6)); s += g[i]; }
        for (int i = 0; i < 3; ++i) T3.t[i] = (float)(g[i]/s);
        double sig = 1.6 * pow(2.0, 1.0/3.0);
        s = 0; for (int i = 0; i < 5; ++i){ double d = i - 2.0; g[i] = exp(-d*d/(2.0*sig*sig)); s += g[i]; }
        for (int i = 0; i < 5; ++i) T5.t[i] = (float)(g[i]/s);
    }

    const dim3 blk(256);

    // prep + pyramid (+3 plane softmaxes) + weight converts/brc + Wrv
    prepx_kernel<<<dim3(64,4,8), blk, 0, stream>>>(x, S, xTb);
    plane6_kernel<<<BB_*CC_, blk, 0, stream>>>(x, P, S + (size_t)BCHW, S + (size_t)2*BCHW, T3, T5);
    cvtWB_kernel<<<144, blk, 0, stream>>>(Wk, Wq, Wr, bv, br, Wkb, Wqb, brc);
    wrw_kernel<<<dim3(4,4,1), blk, 0, stream>>>(Wr, Wv, Wrv);

    // 3 chan-att grams in one launch: z = (g*8+b)*8 + kc, K-chunk 512, f16 partials
    mfma_nt<0,8,1><<<dim3(2,2,192), blk, 0, stream>>>(P, CHW, 4096, S, CHW, 4096,
                                                      partH, 65536, 256, 512, nullptr, nullptr);
    rsa3_kernel<<<BB_*CC_, blk, 0, stream>>>(partH, att);

    // keys = rowsoftmax(Wk@x + bk)  (logits in f16)
    mfma_nt<1,1,1><<<dim3(32,2,8), blk, 0, stream>>>(Wkb, 0, 256, xTb, CHW, 256,
                                                     FreH, CHW, 4096, 256, bk, nullptr);
    rowsm_kernel<<<BB_*CC_, blk, 0, stream>>>(FreH, keysb);
    // KX = keys @ x^T (split-K 8, f32 partials)
    mfma_nt<0,8,0><<<dim3(2,2,64), blk, 0, stream>>>(keysb, CHW, 4096, S, CHW, 4096,
                                                     partK, 65536, 256, 512, nullptr, nullptr);
    reduce8_kernel<<<(BB_*65536)/256, blk, 0, stream>>>(partK, KX);

    // queriesT = softmax over C fused into GEMM epilogue
    qgemm_sm<<<dim3(32,1,8), blk, 0, stream>>>(xTb, Wqb, bq, qTb);

    // Mbb[b,m,k] = bf16( wdw0[m]*(sum_c Wrv[m,c]*KX[b,k,c]) + wdw1[m]*att[b,k,m] )
    nt256_kernel<0,1,1><<<dim3(4,4,8), blk, 0, stream>>>(Wrv, KX, nullptr, att, wdw, Mbb);

    // out = Mbb @ qT^T + wdw0*(br + Wr@bv)
    mfma_nt<3,1,0><<<dim3(32,2,8), blk, 0, stream>>>(Mbb, 65536, 256, qTb, CHW, 256,
                                                     out, CHW, 4096, 256, brc, wdw);
}